// Round 11
// baseline (1120.205 us; speedup 1.0000x reference)
//
#include <hip/hip_runtime.h>
#include <hip/hip_bf16.h>

typedef __attribute__((ext_vector_type(4))) float  f32x4;
typedef __attribute__((ext_vector_type(8))) __bf16 bf16x8;
typedef __attribute__((ext_vector_type(4))) int    i32x4;
typedef __attribute__((ext_vector_type(8))) int    i32x8;
typedef __hip_bfloat16 bf16_t;

#define GT 256
#define BM 128
#define BN 128
#define BK 32

// problem constants
#define NOBJ 2048
#define NREL 16384
#define DIM  1024
#define KOBJ 34816   /* 16384 + 16384 + 2048 */
#define KREL 4096    /* 2048 + 2048 */

#define AS1Q __attribute__((address_space(1)))
#define AS3Q __attribute__((address_space(3)))

__device__ __forceinline__ void gload_lds16(const void* g, void* l) {
    __builtin_amdgcn_global_load_lds((AS1Q void*)const_cast<void*>(g),
                                     (AS3Q void*)l, 16, 0, 0);
}

#define MFMA_BF16 __builtin_amdgcn_mfma_f32_16x16x32_bf16
// all-ones (E8M0 = 127) block scales: plain fp8 matmul at MX rate
#define MFMA_F8(ACC, Af, Bf) \
    ACC = __builtin_amdgcn_mfma_scale_f32_16x16x128_f8f6f4( \
        Af, Bf, ACC, 0, 0, 0, 0x7F7F7F7F, 0, 0x7F7F7F7F)

__device__ __forceinline__ unsigned char fp8_byte(float x) {
    return (unsigned char)(__builtin_amdgcn_cvt_pk_fp8_f32(x, x, 0, false) & 0xFF);
}
__device__ __forceinline__ unsigned pk4_fp8(float a, float b, float c, float d) {
    int v = __builtin_amdgcn_cvt_pk_fp8_f32(a, b, 0, false);
    v = __builtin_amdgcn_cvt_pk_fp8_f32(c, d, v, true);
    return (unsigned)v;
}

// ---------------------------------------------------------------------------
// 128x128 2-phase bf16 kernel — stacked obj-side FCs; fp8 outputs routed to
// fcRel8 (f2,f3) / fcObj8 (f4).  (unchanged; 32 KB LDS, ~3 blocks/CU already)
// ---------------------------------------------------------------------------
__global__ __launch_bounds__(GT)
void gemm_bt_f234(const bf16_t* __restrict__ A, const bf16_t* __restrict__ B,
                  int M, int N, int K, const float* __restrict__ vecM,
                  unsigned char* __restrict__ fcRel8, unsigned char* __restrict__ fcObj8)
{
    __shared__ bf16_t sA[BM * BK];
    __shared__ bf16_t sB[BN * BK];

    const int tid  = threadIdx.x;
    const int lane = tid & 63;
    const int wid  = tid >> 6;
    const int wr = wid >> 1, wc = wid & 1;
    const int l15 = lane & 15, lk = lane >> 4;

    const long rowA0 = (long)blockIdx.x * BM;
    const long rowB0 = (long)blockIdx.y * BN;
    const long ldab  = (long)K * 2;

    const int c0 = tid, c1 = tid + GT;
    const int r0c = c0 >> 2, k0c = (c0 & 3) ^ ((r0c >> 1) & 3);
    const int r1c = c1 >> 2, k1c = (c1 & 3) ^ ((r1c >> 1) & 3);

    const char* gA0 = (const char*)A + (rowA0 + r0c) * ldab + k0c * 16;
    const char* gA1 = (const char*)A + (rowA0 + r1c) * ldab + k1c * 16;
    const char* gB0 = (const char*)B + (rowB0 + r0c) * ldab + k0c * 16;
    const char* gB1 = (const char*)B + (rowB0 + r1c) * ldab + k1c * 16;
    char* lA0 = (char*)sA + c0 * 16;
    char* lA1 = (char*)sA + c1 * 16;
    char* lB0 = (char*)sB + c0 * 16;
    char* lB1 = (char*)sB + c1 * 16;

    f32x4 acc[4][4];
    #pragma unroll
    for (int i = 0; i < 4; i++)
        #pragma unroll
        for (int j = 0; j < 4; j++) acc[i][j] = f32x4{0.f, 0.f, 0.f, 0.f};

    const int ktPer = K / BK;
    for (int kt = 0; kt < ktPer; ++kt) {
        const long kByte = (long)kt * (BK * 2);
        gload_lds16(gA0 + kByte, lA0);
        gload_lds16(gA1 + kByte, lA1);
        gload_lds16(gB0 + kByte, lB0);
        gload_lds16(gB1 + kByte, lB1);
        __syncthreads();

        bf16x8 af[4], bg[4];
        #pragma unroll
        for (int i = 0; i < 4; i++) {
            const int rr = wr * 64 + i * 16 + l15;
            const int kk = lk ^ ((rr >> 1) & 3);
            af[i] = *reinterpret_cast<const bf16x8*>((const char*)sA + rr * 64 + kk * 16);
        }
        #pragma unroll
        for (int j = 0; j < 4; j++) {
            const int rr = wc * 64 + j * 16 + l15;
            const int kk = lk ^ ((rr >> 1) & 3);
            bg[j] = *reinterpret_cast<const bf16x8*>((const char*)sB + rr * 64 + kk * 16);
        }
        #pragma unroll
        for (int i = 0; i < 4; i++)
            #pragma unroll
            for (int j = 0; j < 4; j++)
                acc[i][j] = MFMA_BF16(af[i], bg[j], acc[i][j], 0, 0, 0);
        __syncthreads();
    }

    #pragma unroll
    for (int i = 0; i < 4; i++) {
        const long mBase = rowA0 + wr * 64 + i * 16 + lk * 4;
        const f32x4 vm = *reinterpret_cast<const f32x4*>(&vecM[mBase]);
        #pragma unroll
        for (int r = 0; r < 4; r++) {
            const long m = mBase + r;
            #pragma unroll
            for (int j = 0; j < 4; j++) {
                const long n = rowB0 + wc * 64 + j * 16 + l15;
                const float v = fmaxf(acc[i][j][r] + vm[r], 0.f);
                const unsigned char o = fp8_byte(v);
                if (m < 1024)            fcRel8[m * (long)KREL + n] = o;
                else if (m < 2048)       fcRel8[(m - 1024) * (long)KREL + 2048 + n] = o;
                else                     fcObj8[(m - 2048) * (long)KOBJ + 32768 + n] = o;
            }
        }
    }
}

// ---------------------------------------------------------------------------
// 128x256 bf16 occupancy-first FC kernel (fc01): single-buffer 48 KiB LDS,
// 512 thr (8 waves, 2M x 4N, 64x64 out each) -> 3 blocks/CU.
// LDS[r][c16] = global[r][c16 ^ (r&7)] both-sides swizzle; BK = 64 bf16.
// Epilogue: bf16(relu(acc+bias)) -> fp8 routed into fcObj8 column slices:
//   Cb8[(m&1023)*ldc + (m>>10)*16384 + n]
// ---------------------------------------------------------------------------
__global__ __launch_bounds__(512, 4)
void gemmfc_occ(const bf16_t* __restrict__ A, const bf16_t* __restrict__ B,
                int M, int N, int K, const float* __restrict__ vecM,
                unsigned char* __restrict__ Cb8, int ldc, int Ntiles)
{
    __shared__ __align__(16) char lds[49152];   // A[128][128B] @0, B[256][128B] @16384

    const int tid  = threadIdx.x;
    const int lane = tid & 63;
    const int wid  = tid >> 6;
    const int wr = wid >> 2, wc = wid & 3;
    const int l15 = lane & 15, lk = lane >> 4;

    const int nwg = gridDim.x;
    const int cpx = nwg >> 3;
    const int bid = blockIdx.x;
    const int swz = (bid & 7) * cpx + (bid >> 3);
    const int tm = swz / Ntiles, tn = swz % Ntiles;
    const long rowM0 = (long)tm * 128;
    const long rowN0 = (long)tn * 256;
    const long ld = (long)K * 2;        // bytes per row

    const int NT = K >> 6;              // K-tiles of 64 bf16 (128 B)

    const int rs = tid >> 3;
    const int kc = (tid & 7) ^ (rs & 7);
    const char* gA = (const char*)A + (rowM0 + rs) * ld + kc * 16;
    const char* gB = (const char*)B + (rowN0 + rs) * ld + kc * 16;
    char* lA = (char*)lds + tid * 16;
    char* lB = (char*)lds + 16384 + tid * 16;

    // bf16 frag chunks within a 128 B row: k-half0 -> chunk lk, k-half1 -> 4+lk
    const int xo0 = ((0 + lk) ^ (l15 & 7)) * 16;
    const int xo1 = ((4 + lk) ^ (l15 & 7)) * 16;
    const int baseA = (wr * 64 + l15) * 128;            // + kf*2048
    const int baseB = 16384 + (wc * 64 + l15) * 128;    // + j*2048

    f32x4 acc[4][4];
    #pragma unroll
    for (int i = 0; i < 4; i++)
        #pragma unroll
        for (int j = 0; j < 4; j++) acc[i][j] = f32x4{0.f, 0.f, 0.f, 0.f};

    for (int t = 0; t < NT; ++t) {
        const long kByte = (long)t * 128;
        gload_lds16(gA + kByte, lA);
        gload_lds16(gA + kByte + 64 * ld, lA + 8192);
        #pragma unroll
        for (int i = 0; i < 4; i++)
            gload_lds16(gB + kByte + (long)i * 64 * ld, lB + i * 8192);
        __syncthreads();

        bf16x8 a[4][2];
        #pragma unroll
        for (int kf = 0; kf < 4; kf++) {
            a[kf][0] = *(const bf16x8*)((const char*)lds + baseA + kf * 2048 + xo0);
            a[kf][1] = *(const bf16x8*)((const char*)lds + baseA + kf * 2048 + xo1);
        }
        #pragma unroll
        for (int j = 0; j < 4; j++) {
            const bf16x8 b0 = *(const bf16x8*)((const char*)lds + baseB + j * 2048 + xo0);
            const bf16x8 b1 = *(const bf16x8*)((const char*)lds + baseB + j * 2048 + xo1);
            #pragma unroll
            for (int kf = 0; kf < 4; kf++) {
                acc[kf][j] = MFMA_BF16(a[kf][0], b0, acc[kf][j], 0, 0, 0);
                acc[kf][j] = MFMA_BF16(a[kf][1], b1, acc[kf][j], 0, 0, 0);
            }
        }
        __syncthreads();
    }

    #pragma unroll
    for (int kf = 0; kf < 4; kf++) {
        const long m0 = rowM0 + wr * 64 + kf * 16 + lk * 4;
        const f32x4 vm = *reinterpret_cast<const f32x4*>(vecM + m0);
        #pragma unroll
        for (int r = 0; r < 4; r++) {
            const long m = m0 + r;
            #pragma unroll
            for (int j = 0; j < 4; j++) {
                const long n = rowN0 + wc * 64 + j * 16 + l15;
                const float o = fmaxf(acc[kf][j][r] + vm[r], 0.f);
                Cb8[(m & 1023) * (long)ldc + (m >> 10) * 16384 + n] = fp8_byte(o);
            }
        }
    }
}

// ---------------------------------------------------------------------------
// 128x256 MX-fp8 collect kernel, occupancy-first (unchanged from R10).
// Cf[m*ldc+n] += acc * scale   (atomicAdd when gridDim.z>1)
// ---------------------------------------------------------------------------
__global__ __launch_bounds__(512, 4)
void gemmf8_occ(const unsigned char* __restrict__ A, const unsigned char* __restrict__ B,
                int M, int N, int K, float* __restrict__ Cf, float scale,
                int ldc, int Ntiles)
{
    __shared__ __align__(16) char lds[49152];   // A[128][128B] @0, B[256][128B] @16384

    const int tid  = threadIdx.x;
    const int lane = tid & 63;
    const int wid  = tid >> 6;
    const int wr = wid >> 2, wc = wid & 3;
    const int l15 = lane & 15, lk = lane >> 4;

    const int nwg = gridDim.x;
    const int cpx = nwg >> 3;
    const int bid = blockIdx.x;
    const int swz = (bid & 7) * cpx + (bid >> 3);
    const int tm = swz / Ntiles, tn = swz % Ntiles;
    const long rowM0 = (long)tm * 128;
    const long rowN0 = (long)tn * 256;
    const long ld = (long)K;            // bytes per row

    const int nz = gridDim.z;
    const int NT = (K >> 7) / nz;       // K-tiles of 128 bytes
    const long kb0 = (long)NT * blockIdx.z * 128;

    const int rs = tid >> 3;                    // 0..63
    const int kc = (tid & 7) ^ (rs & 7);
    const char* gA = (const char*)A + (rowM0 + rs) * ld + kb0 + kc * 16;
    const char* gB = (const char*)B + (rowN0 + rs) * ld + kb0 + kc * 16;
    char* lA = (char*)lds + tid * 16;
    char* lB = (char*)lds + 16384 + tid * 16;

    const int xc0 = ((2 * lk + 0) ^ (l15 & 7)) * 16;
    const int xc1 = ((2 * lk + 1) ^ (l15 & 7)) * 16;
    const int baseA = (wr * 64 + l15) * 128;            // + kf*2048
    const int baseB = 16384 + (wc * 64 + l15) * 128;    // + j*2048

#define LDF8(dst, off) { \
    i32x4 lo_ = *(const i32x4*)((const char*)lds + (off) + xc0); \
    i32x4 hi_ = *(const i32x4*)((const char*)lds + (off) + xc1); \
    dst = __builtin_shufflevector(lo_, hi_, 0, 1, 2, 3, 4, 5, 6, 7); }

    f32x4 acc[4][4];
    #pragma unroll
    for (int i = 0; i < 4; i++)
        #pragma unroll
        for (int j = 0; j < 4; j++) acc[i][j] = f32x4{0.f, 0.f, 0.f, 0.f};

    for (int t = 0; t < NT; ++t) {
        const long kByte = (long)t * 128;
        gload_lds16(gA + kByte, lA);
        gload_lds16(gA + kByte + 64 * ld, lA + 8192);
        #pragma unroll
        for (int i = 0; i < 4; i++)
            gload_lds16(gB + kByte + (long)i * 64 * ld, lB + i * 8192);
        __syncthreads();

        i32x8 a[4];
        #pragma unroll
        for (int kf = 0; kf < 4; kf++) LDF8(a[kf], baseA + kf * 2048);
        #pragma unroll
        for (int j = 0; j < 4; j++) {
            i32x8 b;
            LDF8(b, baseB + j * 2048);
            #pragma unroll
            for (int kf = 0; kf < 4; kf++) MFMA_F8(acc[kf][j], a[kf], b);
        }
        __syncthreads();
    }
#undef LDF8

    #pragma unroll
    for (int kf = 0; kf < 4; kf++) {
        const long m0 = rowM0 + wr * 64 + kf * 16 + lk * 4;
        #pragma unroll
        for (int r = 0; r < 4; r++) {
            const long m = m0 + r;
            #pragma unroll
            for (int j = 0; j < 4; j++) {
                const long n = rowN0 + wc * 64 + j * 16 + l15;
                const float v = acc[kf][j][r] * scale;
                if (nz == 1) Cf[m * (long)ldc + n] += v;
                else atomicAdd(&Cf[m * (long)ldc + n], v);
            }
        }
    }
}

__global__ __launch_bounds__(256)
void k_cast_bf16(const float* __restrict__ in, bf16_t* __restrict__ out, long n)
{
    const long stride = (long)gridDim.x * blockDim.x;
    for (long i = (long)blockIdx.x * blockDim.x + threadIdx.x; i * 4 < n; i += stride) {
        f32x4 v = *reinterpret_cast<const f32x4*>(in + i * 4);
        union { bf16_t h[4]; ushort4 u; } o;
        o.h[0] = __float2bfloat16(v[0]); o.h[1] = __float2bfloat16(v[1]);
        o.h[2] = __float2bfloat16(v[2]); o.h[3] = __float2bfloat16(v[3]);
        *reinterpret_cast<ushort4*>(out + i * 4) = o.u;
    }
}

// Pass 1: row-sum (+ optional col-sum) partials of f32 attn via atomics.
template<bool COLS>
__global__ __launch_bounds__(256)
void k_sums(const float* __restrict__ in, int C,
            float* __restrict__ rowsum, float* __restrict__ colsum)
{
    __shared__ float cpart[16][64];
    __shared__ float rpart[64][17];
    const int tid = threadIdx.x;
    const int tx  = tid & 15;
    const int ty  = tid >> 4;
    const long c0 = (long)blockIdx.x * 64;
    const long r0 = (long)blockIdx.y * 64;

    float cs0 = 0.f, cs1 = 0.f, cs2 = 0.f, cs3 = 0.f;
    #pragma unroll
    for (int i = 0; i < 4; i++) {
        const int r = i * 16 + ty;
        const f32x4 v = *reinterpret_cast<const f32x4*>(&in[(r0 + r) * (long)C + c0 + tx * 4]);
        rpart[r][tx] = v[0] + v[1] + v[2] + v[3];
        cs0 += v[0]; cs1 += v[1]; cs2 += v[2]; cs3 += v[3];
    }
    if (COLS) {
        cpart[ty][tx * 4 + 0] = cs0;
        cpart[ty][tx * 4 + 1] = cs1;
        cpart[ty][tx * 4 + 2] = cs2;
        cpart[ty][tx * 4 + 3] = cs3;
    }
    __syncthreads();
    if (tid < 64) {
        float rs = 0.f;
        #pragma unroll
        for (int k = 0; k < 16; k++) rs += rpart[tid][k];
        atomicAdd(&rowsum[r0 + tid], rs);
        if (COLS) {
            float cs = 0.f;
            #pragma unroll
            for (int k = 0; k < 16; k++) cs += cpart[k][tid];
            atomicAdd(&colsum[c0 + tid], cs);
        }
    }
}

__global__ __launch_bounds__(256)
void k_invscale(float* __restrict__ s, int n, float c)
{
    const int i = blockIdx.x * 256 + threadIdx.x;
    if (i < n) s[i] = c / (s[i] + 1e-7f);
}

// Pass 2: fp8 operands in concat layouts (scales pre-folded incl 2^13 / 2^11).
template<bool TRANS>
__global__ __launch_bounds__(256)
void k_prep2f8(const float* __restrict__ in, int C,
               unsigned char* __restrict__ Aobj, unsigned char* __restrict__ Arel,
               const float* __restrict__ invRow, const float* __restrict__ invCol)
{
    __shared__ float tile[64][65];
    const int tid = threadIdx.x;
    const int tx  = tid & 15;
    const int ty  = tid >> 4;
    const long c0 = (long)blockIdx.x * 64;
    const long r0 = (long)blockIdx.y * 64;

    #pragma unroll
    for (int i = 0; i < 4; i++) {
        const int r = i * 16 + ty;
        const f32x4 v = *reinterpret_cast<const f32x4*>(&in[(r0 + r) * (long)C + c0 + tx * 4]);
        const float sc = invRow[r0 + r];
        *reinterpret_cast<unsigned*>(&Aobj[(r0 + r) * (long)KOBJ + c0 + tx * 4]) =
            pk4_fp8(v[0] * sc, v[1] * sc, v[2] * sc, v[3] * sc);
        if (TRANS) *reinterpret_cast<f32x4*>(&tile[r][tx * 4]) = v;
    }
    if (TRANS) {
        __syncthreads();
        const int rr = tid & 63;
        const int cg = tid >> 6;
        #pragma unroll
        for (int i = 0; i < 16; i++) {
            const int c = cg * 16 + i;
            const float sc = invCol[c0 + c];
            Arel[(c0 + c) * (long)KREL + r0 + rr] = fp8_byte(tile[rr][c] * sc);
        }
    }
}

extern "C" void kernel_launch(void* const* d_in, const int* in_sizes, int n_in,
                              void* d_out, int out_size, void* d_ws, size_t ws_size,
                              hipStream_t stream)
{
    if (n_in < 15) return;
    const float* obj_feats = (const float*)d_in[0];
    const float* rel_feats = (const float*)d_in[1];
    const float* attn_sub  = (const float*)d_in[2];
    const float* attn_obj  = (const float*)d_in[3];
    const float* attn_self = (const float*)d_in[4];
    const float* Wf[5] = { (const float*)d_in[5], (const float*)d_in[7],
                           (const float*)d_in[9], (const float*)d_in[11], (const float*)d_in[13] };
    const float* Bf[5] = { (const float*)d_in[6], (const float*)d_in[8],
                           (const float*)d_in[10], (const float*)d_in[12], (const float*)d_in[14] };

    const int NO = NOBJ, NR = NREL, D = DIM;

    char* w = (char*)d_ws;
    auto take = [&](size_t bytes) { char* p = w; w += bytes; return p; };
    unsigned char* Aobj8  = (unsigned char*)take((size_t)NO * KOBJ);   // [2048][34816] fp8
    unsigned char* Arel8  = (unsigned char*)take((size_t)NR * KREL);   // [16384][4096] fp8
    unsigned char* fcObj8 = (unsigned char*)take((size_t)D * KOBJ);    // [1024][34816] fp8
    unsigned char* fcRel8 = (unsigned char*)take((size_t)D * KREL);    // [1024][4096]  fp8
    bf16_t* xrel_bf = (bf16_t*)take((size_t)NR * D * 2);
    bf16_t* xobj_bf = (bf16_t*)take((size_t)NO * D * 2);
    bf16_t* Wstk01  = (bf16_t*)take((size_t)2 * D * D * 2);
    bf16_t* Wstk234 = (bf16_t*)take((size_t)3 * D * D * 2);
    float*  b01     = (float*)take((size_t)2 * D * 4);
    float*  bstk    = (float*)take((size_t)3 * D * 4);
    float*  sums    = (float*)take((size_t)(3 * NO + 2 * NR) * 4);
    float* invS     = sums;            // 2^13 * (1/3)/(rowsum+eps)
    float* invO     = sums + NO;
    float* invSelf  = sums + 2 * NO;
    float* invTS    = sums + 3 * NO;   // 2^11 * 0.5/(colsum+eps)
    float* invTO    = sums + 3 * NO + NR;
    if ((size_t)(w - (char*)d_ws) > ws_size) return;   // ws too small: fail loudly

    float* x_obj = (float*)d_out;
    float* x_rel = x_obj + (size_t)NO * D;

    hipMemcpyAsync(x_obj, obj_feats, (size_t)NO * D * 4, hipMemcpyDeviceToDevice, stream);
    hipMemcpyAsync(x_rel, rel_feats, (size_t)NR * D * 4, hipMemcpyDeviceToDevice, stream);
    hipMemcpyAsync(b01,     Bf[0], (size_t)D * 4, hipMemcpyDeviceToDevice, stream);
    hipMemcpyAsync(b01 + D, Bf[1], (size_t)D * 4, hipMemcpyDeviceToDevice, stream);
    for (int i = 0; i < 3; i++)
        hipMemcpyAsync(bstk + i * D, Bf[2 + i], (size_t)D * 4, hipMemcpyDeviceToDevice, stream);
    hipMemsetAsync(sums, 0, (size_t)(3 * NO + 2 * NR) * 4, stream);

    auto cast = [&](const float* in, bf16_t* out, long n) {
        long blocks = (n / 4 + 255) / 256; if (blocks > 4096) blocks = 4096;
        k_cast_bf16<<<dim3((unsigned)blocks), dim3(256), 0, stream>>>(in, out, n);
    };
    cast(Wf[0], Wstk01,                 (long)D * D);
    cast(Wf[1], Wstk01 + (size_t)D * D, (long)D * D);
    for (int i = 0; i < 3; i++)
        cast(Wf[2 + i], Wstk234 + (size_t)i * D * D, (long)D * D);

    // pass 1: exact f32 row/col sums
    k_sums<true><<<dim3(NR / 64, NO / 64), dim3(256), 0, stream>>>(attn_sub, NR, invS, invTS);
    k_sums<true><<<dim3(NR / 64, NO / 64), dim3(256), 0, stream>>>(attn_obj, NR, invO, invTO);
    k_sums<false><<<dim3(NO / 64, NO / 64), dim3(256), 0, stream>>>(attn_self, NO, invSelf, nullptr);
    // fold global power-of-2 into the fp8 quantization scale
    k_invscale<<<dim3((3 * NO + 255) / 256), dim3(256), 0, stream>>>(sums, 3 * NO, 8192.f / 3.f);
    k_invscale<<<dim3((2 * NR + 255) / 256), dim3(256), 0, stream>>>(sums + 3 * NO, 2 * NR, 1024.f);

    // pass 2: fp8 operands in concat layouts
    k_prep2f8<true><<<dim3(NR / 64, NO / 64), dim3(256), 0, stream>>>(
        attn_sub, NR, Aobj8, Arel8, invS, invTS);
    k_prep2f8<true><<<dim3(NR / 64, NO / 64), dim3(256), 0, stream>>>(
        attn_obj, NR, Aobj8 + 16384, Arel8 + 2048, invO, invTO);
    k_prep2f8<false><<<dim3(NO / 64, NO / 64), dim3(256), 0, stream>>>(
        attn_self, NO, Aobj8 + 32768, nullptr, invSelf, nullptr);

    for (int step = 0; step < 2; ++step) {
        cast(x_obj, xobj_bf, (long)NO * D);
        cast(x_rel, xrel_bf, (long)NR * D);

        // fcObj cols [0,32768): [f0|f1] = relu([W0;W1] @ xrel^T + b01) -> fp8
        // occupancy-first: 1024 wg, 48 KiB LDS -> 3 blocks/CU
        gemmfc_occ<<<dim3((2 * D / 128) * (NR / 256), 1, 1), dim3(512), 0, stream>>>(
            Wstk01, xrel_bf, 2 * D, NR, D, b01, fcObj8, KOBJ, NR / 256);
        // fcRel [f2|f3] + fcObj col [32768,34816) (f4) -> fp8
        gemm_bt_f234<<<dim3(3 * D / BM, NO / BN, 1), dim3(GT), 0, stream>>>(
            Wstk234, xobj_bf, 3 * D, NO, D, bstk, fcRel8, fcObj8);

        // x_obj += (Aobj8 @ fcObj8^T) * 2^-13   (z=16 -> 1024 wg, NT=17)
        gemmf8_occ<<<dim3((NO / 128) * (D / 256), 1, 16), dim3(512), 0, stream>>>(
            Aobj8, fcObj8, NO, D, KOBJ, x_obj, 1.f / 8192.f, D, D / 256);
        // x_rel += (Arel8 @ fcRel8^T) * 2^-11   (z=2 -> 1024 wg, NT=16)
        gemmf8_occ<<<dim3((NR / 128) * (D / 256), 1, 2), dim3(512), 0, stream>>>(
            Arel8, fcRel8, NR, D, KREL, x_rel, 1.f / 2048.f, D, D / 256);
    }
}

// Round 12
// 859.374 us; speedup vs baseline: 1.3035x; 1.3035x over previous
//
#include <hip/hip_runtime.h>
#include <hip/hip_bf16.h>

typedef __attribute__((ext_vector_type(4))) float  f32x4;
typedef __attribute__((ext_vector_type(8))) __bf16 bf16x8;
typedef __attribute__((ext_vector_type(4))) int    i32x4;
typedef __attribute__((ext_vector_type(8))) int    i32x8;
typedef __hip_bfloat16 bf16_t;

#define GT 256
#define BM 128
#define BN 128
#define BK 32

// problem constants
#define NOBJ 2048
#define NREL 16384
#define DIM  1024
#define KOBJ 34816   /* 16384 + 16384 + 2048 */
#define KREL 4096    /* 2048 + 2048 */

#define AS1Q __attribute__((address_space(1)))
#define AS3Q __attribute__((address_space(3)))

__device__ __forceinline__ void gload_lds16(const void* g, void* l) {
    __builtin_amdgcn_global_load_lds((AS1Q void*)const_cast<void*>(g),
                                     (AS3Q void*)l, 16, 0, 0);
}

#define MFMA_BF16 __builtin_amdgcn_mfma_f32_16x16x32_bf16
// all-ones (E8M0 = 127) block scales: plain fp8 matmul at MX rate
#define MFMA_F8(ACC, Af, Bf) \
    ACC = __builtin_amdgcn_mfma_scale_f32_16x16x128_f8f6f4( \
        Af, Bf, ACC, 0, 0, 0, 0x7F7F7F7F, 0, 0x7F7F7F7F)

#define VMCNT(N) asm volatile("s_waitcnt vmcnt(" #N ")" ::: "memory")
#define SBAR()   __builtin_amdgcn_sched_barrier(0)

__device__ __forceinline__ unsigned char fp8_byte(float x) {
    return (unsigned char)(__builtin_amdgcn_cvt_pk_fp8_f32(x, x, 0, false) & 0xFF);
}
__device__ __forceinline__ unsigned pk4_fp8(float a, float b, float c, float d) {
    int v = __builtin_amdgcn_cvt_pk_fp8_f32(a, b, 0, false);
    v = __builtin_amdgcn_cvt_pk_fp8_f32(c, d, v, true);
    return (unsigned)v;
}

// ---------------------------------------------------------------------------
// 128x128 2-phase bf16 kernel — stacked obj-side FCs; fp8 outputs routed to
// fcRel8 (f2,f3) / fcObj8 (f4).  (unchanged)
// ---------------------------------------------------------------------------
__global__ __launch_bounds__(GT)
void gemm_bt_f234(const bf16_t* __restrict__ A, const bf16_t* __restrict__ B,
                  int M, int N, int K, const float* __restrict__ vecM,
                  unsigned char* __restrict__ fcRel8, unsigned char* __restrict__ fcObj8)
{
    __shared__ bf16_t sA[BM * BK];
    __shared__ bf16_t sB[BN * BK];

    const int tid  = threadIdx.x;
    const int lane = tid & 63;
    const int wid  = tid >> 6;
    const int wr = wid >> 1, wc = wid & 1;
    const int l15 = lane & 15, lk = lane >> 4;

    const long rowA0 = (long)blockIdx.x * BM;
    const long rowB0 = (long)blockIdx.y * BN;
    const long ldab  = (long)K * 2;

    const int c0 = tid, c1 = tid + GT;
    const int r0c = c0 >> 2, k0c = (c0 & 3) ^ ((r0c >> 1) & 3);
    const int r1c = c1 >> 2, k1c = (c1 & 3) ^ ((r1c >> 1) & 3);

    const char* gA0 = (const char*)A + (rowA0 + r0c) * ldab + k0c * 16;
    const char* gA1 = (const char*)A + (rowA0 + r1c) * ldab + k1c * 16;
    const char* gB0 = (const char*)B + (rowB0 + r0c) * ldab + k0c * 16;
    const char* gB1 = (const char*)B + (rowB0 + r1c) * ldab + k1c * 16;
    char* lA0 = (char*)sA + c0 * 16;
    char* lA1 = (char*)sA + c1 * 16;
    char* lB0 = (char*)sB + c0 * 16;
    char* lB1 = (char*)sB + c1 * 16;

    f32x4 acc[4][4];
    #pragma unroll
    for (int i = 0; i < 4; i++)
        #pragma unroll
        for (int j = 0; j < 4; j++) acc[i][j] = f32x4{0.f, 0.f, 0.f, 0.f};

    const int ktPer = K / BK;
    for (int kt = 0; kt < ktPer; ++kt) {
        const long kByte = (long)kt * (BK * 2);
        gload_lds16(gA0 + kByte, lA0);
        gload_lds16(gA1 + kByte, lA1);
        gload_lds16(gB0 + kByte, lB0);
        gload_lds16(gB1 + kByte, lB1);
        __syncthreads();

        bf16x8 af[4], bg[4];
        #pragma unroll
        for (int i = 0; i < 4; i++) {
            const int rr = wr * 64 + i * 16 + l15;
            const int kk = lk ^ ((rr >> 1) & 3);
            af[i] = *reinterpret_cast<const bf16x8*>((const char*)sA + rr * 64 + kk * 16);
        }
        #pragma unroll
        for (int j = 0; j < 4; j++) {
            const int rr = wc * 64 + j * 16 + l15;
            const int kk = lk ^ ((rr >> 1) & 3);
            bg[j] = *reinterpret_cast<const bf16x8*>((const char*)sB + rr * 64 + kk * 16);
        }
        #pragma unroll
        for (int i = 0; i < 4; i++)
            #pragma unroll
            for (int j = 0; j < 4; j++)
                acc[i][j] = MFMA_BF16(af[i], bg[j], acc[i][j], 0, 0, 0);
        __syncthreads();
    }

    #pragma unroll
    for (int i = 0; i < 4; i++) {
        const long mBase = rowA0 + wr * 64 + i * 16 + lk * 4;
        const f32x4 vm = *reinterpret_cast<const f32x4*>(&vecM[mBase]);
        #pragma unroll
        for (int r = 0; r < 4; r++) {
            const long m = mBase + r;
            #pragma unroll
            for (int j = 0; j < 4; j++) {
                const long n = rowB0 + wc * 64 + j * 16 + l15;
                const float v = fmaxf(acc[i][j][r] + vm[r], 0.f);
                const unsigned char o = fp8_byte(v);
                if (m < 1024)            fcRel8[m * (long)KREL + n] = o;
                else if (m < 2048)       fcRel8[(m - 1024) * (long)KREL + 2048 + n] = o;
                else                     fcObj8[(m - 2048) * (long)KOBJ + 32768 + n] = o;
            }
        }
    }
}

// ---------------------------------------------------------------------------
// 256x256 bf16 kernel, deep-prefetch 2-phase pipeline (fc01).  (R10 version)
// ---------------------------------------------------------------------------
__global__ __launch_bounds__(512, 2)
void gemm256fc(const bf16_t* __restrict__ A, const bf16_t* __restrict__ B,
               int M, int N, int K, const float* __restrict__ vecM,
               unsigned char* __restrict__ Cb8, int ldc, int Ntiles)
{
    __shared__ __align__(16) char lds[131072];

    const int tid  = threadIdx.x;
    const int lane = tid & 63;
    const int wid  = tid >> 6;
    const int wr = wid >> 2, wc = wid & 3;
    const int l15 = lane & 15, lk = lane >> 4;

    const int nwg = gridDim.x;
    const int cpx = nwg >> 3;
    const int bid = blockIdx.x;
    const int swz = (bid & 7) * cpx + (bid >> 3);
    const int tm = swz / Ntiles, tn = swz % Ntiles;
    const long rowM0 = (long)tm * 256;
    const long rowN0 = (long)tn * 256;
    const long ld = (long)K * 2;

    const int NT = K >> 6;

    const int rl = tid >> 3;
    const int lc = (tid & 7) ^ (rl & 7);
    const char* gA0 = (const char*)A + (rowM0 + rl) * ld + lc * 16;
    const char* gB0 = (const char*)B + (rowN0 + rl) * ld + lc * 16;

    auto stage = [&](int buf, int isB, int h, int t) {
        const char* g = (isB ? gB0 : gA0) + (long)h * 128 * ld + (long)t * 128;
        char* l = (char*)lds + buf * 65536 + isB * 32768 + h * 16384 + tid * 16;
        gload_lds16(g, l);
        gload_lds16(g + 64 * ld, l + 8192);
    };

    const int xo0 = ((0 + lk) ^ (l15 & 7)) * 16;
    const int xo1 = ((4 + lk) ^ (l15 & 7)) * 16;
    const int baseA = (wr * 16 + l15) * 128;
    const int baseB = 32768 + (wc * 16 + l15) * 128;

    f32x4 acc[8][4];
    #pragma unroll
    for (int i = 0; i < 8; i++)
        #pragma unroll
        for (int j = 0; j < 4; j++) acc[i][j] = f32x4{0.f, 0.f, 0.f, 0.f};

    stage(0, 0, 0, 0); stage(0, 1, 0, 0); stage(0, 1, 1, 0); stage(0, 0, 1, 0);

    bf16x8 a[4][2], b[4][2];
    for (int t = 0; t < NT; ++t) {
        const int cur = t & 1;
        const int nxt = cur ^ 1;
        const bool pf = (t + 1) < NT;
        const char* lcur = (const char*)lds + (cur << 16);

        if (pf) { stage(nxt, 0, 0, t + 1); stage(nxt, 1, 0, t + 1);
                  stage(nxt, 1, 1, t + 1); stage(nxt, 0, 1, t + 1); }
        if (pf) { VMCNT(10); } else { VMCNT(2); }
        SBAR();
        __builtin_amdgcn_s_barrier();                 // bar1: A0,B0,B1(t) visible

        #pragma unroll
        for (int kf = 0; kf < 4; kf++) {
            a[kf][0] = *(const bf16x8*)(lcur + baseA + kf * 4096 + xo0);
            a[kf][1] = *(const bf16x8*)(lcur + baseA + kf * 4096 + xo1);
        }
        #pragma unroll
        for (int j = 0; j < 4; j++) {
            b[j][0] = *(const bf16x8*)(lcur + baseB + j * 8192 + xo0);
            b[j][1] = *(const bf16x8*)(lcur + baseB + j * 8192 + xo1);
        }
        asm volatile("s_waitcnt lgkmcnt(0)" ::: "memory");
        SBAR();
        __builtin_amdgcn_s_setprio(1);
        #pragma unroll
        for (int j = 0; j < 4; j++)
            #pragma unroll
            for (int kf = 0; kf < 4; kf++) {
                acc[kf][j] = MFMA_BF16(a[kf][0], b[j][0], acc[kf][j], 0, 0, 0);
                acc[kf][j] = MFMA_BF16(a[kf][1], b[j][1], acc[kf][j], 0, 0, 0);
            }
        __builtin_amdgcn_s_setprio(0);
        if (pf) { VMCNT(8); } else { VMCNT(0); }
        SBAR();
        __builtin_amdgcn_s_barrier();                 // bar2: A1(t) visible

        #pragma unroll
        for (int kf = 0; kf < 4; kf++) {
            a[kf][0] = *(const bf16x8*)(lcur + baseA + (4 + kf) * 4096 + xo0);
            a[kf][1] = *(const bf16x8*)(lcur + baseA + (4 + kf) * 4096 + xo1);
        }
        asm volatile("s_waitcnt lgkmcnt(0)" ::: "memory");
        SBAR();
        __builtin_amdgcn_s_barrier();                 // bar3: cur fully read
        __builtin_amdgcn_s_setprio(1);
        #pragma unroll
        for (int j = 0; j < 4; j++)
            #pragma unroll
            for (int kf = 0; kf < 4; kf++) {
                acc[4 + kf][j] = MFMA_BF16(a[kf][0], b[j][0], acc[4 + kf][j], 0, 0, 0);
                acc[4 + kf][j] = MFMA_BF16(a[kf][1], b[j][1], acc[4 + kf][j], 0, 0, 0);
            }
        __builtin_amdgcn_s_setprio(0);
    }

    #pragma unroll
    for (int kf = 0; kf < 8; kf++) {
        const long m0 = rowM0 + wr * 16 + kf * 32 + lk * 4;
        const f32x4 vm = *reinterpret_cast<const f32x4*>(vecM + m0);
        #pragma unroll
        for (int r = 0; r < 4; r++) {
            const long m = m0 + r;
            #pragma unroll
            for (int j = 0; j < 4; j++) {
                const long n = rowN0 + wc * 16 + j * 64 + l15;
                const float o = fmaxf(acc[kf][j][r] + vm[r], 0.f);
                Cb8[(m & 1023) * (long)ldc + (m >> 10) * 16384 + n] = fp8_byte(o);
            }
        }
    }
}

// ---------------------------------------------------------------------------
// Dual-role 128x256 MX-fp8 collect kernel (one dispatch = both collects).
// 1024 blocks: role by swizzled id s: s<512 -> colObj (z=s>>6, tile=s&63,
// K=KOBJ, NT=34, atomicAdd, scale 2^-13); s>=512 -> colRel (tile=s-512,
// K=KREL, NT=32, plain +=, scale 2^-11).  48 KiB LDS -> 3 blocks/CU, grid
// gives 4/CU of schedulable work with ZERO extra output traffic.
// ---------------------------------------------------------------------------
__global__ __launch_bounds__(512, 4)
void gemmf8_dual(const unsigned char* __restrict__ Ao, const unsigned char* __restrict__ Bo,
                 float* __restrict__ Co,
                 const unsigned char* __restrict__ Ar, const unsigned char* __restrict__ Br,
                 float* __restrict__ Cr)
{
    __shared__ __align__(16) char lds[49152];   // A[128][128B] @0, B[256][128B] @16384

    const int tid  = threadIdx.x;
    const int lane = tid & 63;
    const int wid  = tid >> 6;
    const int wr = wid >> 2, wc = wid & 3;
    const int l15 = lane & 15, lk = lane >> 4;

    const int bid = blockIdx.x;                 // 1024, %8==0
    const int s   = (bid & 7) * 128 + (bid >> 3);

    const unsigned char* A; const unsigned char* B; float* C;
    int K, NT; long kb0; float scale; bool at;
    long rowM0, rowN0;
    if (s < 512) {          // colObj: x_obj += (Aobj @ fcObj^T) * 2^-13
        const int zz = s >> 6, t = s & 63;      // 8 z-slices x 64 tiles (16x4)
        rowM0 = (long)(t >> 2) * 128; rowN0 = (long)(t & 3) * 256;
        A = Ao; B = Bo; C = Co;
        K = KOBJ; NT = 34; kb0 = (long)34 * zz * 128;
        scale = 1.f / 8192.f; at = true;
    } else {                // colRel: x_rel += (Arel @ fcRel^T) * 2^-11
        const int t = s - 512;                  // 512 tiles (128x4)
        rowM0 = (long)(t >> 2) * 128; rowN0 = (long)(t & 3) * 256;
        A = Ar; B = Br; C = Cr;
        K = KREL; NT = 32; kb0 = 0;
        scale = 1.f / 2048.f; at = false;
    }
    const long ld = (long)K;            // bytes per row

    const int rs = tid >> 3;                    // 0..63
    const int kc = (tid & 7) ^ (rs & 7);
    const char* gA = (const char*)A + (rowM0 + rs) * ld + kb0 + kc * 16;
    const char* gB = (const char*)B + (rowN0 + rs) * ld + kb0 + kc * 16;
    char* lA = (char*)lds + tid * 16;
    char* lB = (char*)lds + 16384 + tid * 16;

    const int xc0 = ((2 * lk + 0) ^ (l15 & 7)) * 16;
    const int xc1 = ((2 * lk + 1) ^ (l15 & 7)) * 16;
    const int baseA = (wr * 64 + l15) * 128;            // + kf*2048
    const int baseB = 16384 + (wc * 64 + l15) * 128;    // + j*2048

#define LDF8(dst, off) { \
    i32x4 lo_ = *(const i32x4*)((const char*)lds + (off) + xc0); \
    i32x4 hi_ = *(const i32x4*)((const char*)lds + (off) + xc1); \
    dst = __builtin_shufflevector(lo_, hi_, 0, 1, 2, 3, 4, 5, 6, 7); }

    f32x4 acc[4][4];
    #pragma unroll
    for (int i = 0; i < 4; i++)
        #pragma unroll
        for (int j = 0; j < 4; j++) acc[i][j] = f32x4{0.f, 0.f, 0.f, 0.f};

    for (int t = 0; t < NT; ++t) {
        const long kByte = (long)t * 128;
        gload_lds16(gA + kByte, lA);
        gload_lds16(gA + kByte + 64 * ld, lA + 8192);
        #pragma unroll
        for (int i = 0; i < 4; i++)
            gload_lds16(gB + kByte + (long)i * 64 * ld, lB + i * 8192);
        __syncthreads();   // compiler drains vmcnt+lgkmcnt here

        i32x8 a[4];
        #pragma unroll
        for (int kf = 0; kf < 4; kf++) LDF8(a[kf], baseA + kf * 2048);
        #pragma unroll
        for (int j = 0; j < 4; j++) {
            i32x8 b;
            LDF8(b, baseB + j * 2048);
            #pragma unroll
            for (int kf = 0; kf < 4; kf++) MFMA_F8(acc[kf][j], a[kf], b);
        }
        __syncthreads();
    }
#undef LDF8

    #pragma unroll
    for (int kf = 0; kf < 4; kf++) {
        const long m0 = rowM0 + wr * 64 + kf * 16 + lk * 4;
        #pragma unroll
        for (int r = 0; r < 4; r++) {
            const long m = m0 + r;
            #pragma unroll
            for (int j = 0; j < 4; j++) {
                const long n = rowN0 + wc * 64 + j * 16 + l15;
                const float v = acc[kf][j][r] * scale;
                if (at) atomicAdd(&C[m * (long)DIM + n], v);
                else    C[m * (long)DIM + n] += v;
            }
        }
    }
}

__global__ __launch_bounds__(256)
void k_cast_bf16(const float* __restrict__ in, bf16_t* __restrict__ out, long n)
{
    const long stride = (long)gridDim.x * blockDim.x;
    for (long i = (long)blockIdx.x * blockDim.x + threadIdx.x; i * 4 < n; i += stride) {
        f32x4 v = *reinterpret_cast<const f32x4*>(in + i * 4);
        union { bf16_t h[4]; ushort4 u; } o;
        o.h[0] = __float2bfloat16(v[0]); o.h[1] = __float2bfloat16(v[1]);
        o.h[2] = __float2bfloat16(v[2]); o.h[3] = __float2bfloat16(v[3]);
        *reinterpret_cast<ushort4*>(out + i * 4) = o.u;
    }
}

// Pass 1: row-sum (+ optional col-sum) partials of f32 attn via atomics.
template<bool COLS>
__global__ __launch_bounds__(256)
void k_sums(const float* __restrict__ in, int C,
            float* __restrict__ rowsum, float* __restrict__ colsum)
{
    __shared__ float cpart[16][64];
    __shared__ float rpart[64][17];
    const int tid = threadIdx.x;
    const int tx  = tid & 15;
    const int ty  = tid >> 4;
    const long c0 = (long)blockIdx.x * 64;
    const long r0 = (long)blockIdx.y * 64;

    float cs0 = 0.f, cs1 = 0.f, cs2 = 0.f, cs3 = 0.f;
    #pragma unroll
    for (int i = 0; i < 4; i++) {
        const int r = i * 16 + ty;
        const f32x4 v = *reinterpret_cast<const f32x4*>(&in[(r0 + r) * (long)C + c0 + tx * 4]);
        rpart[r][tx] = v[0] + v[1] + v[2] + v[3];
        cs0 += v[0]; cs1 += v[1]; cs2 += v[2]; cs3 += v[3];
    }
    if (COLS) {
        cpart[ty][tx * 4 + 0] = cs0;
        cpart[ty][tx * 4 + 1] = cs1;
        cpart[ty][tx * 4 + 2] = cs2;
        cpart[ty][tx * 4 + 3] = cs3;
    }
    __syncthreads();
    if (tid < 64) {
        float rs = 0.f;
        #pragma unroll
        for (int k = 0; k < 16; k++) rs += rpart[tid][k];
        atomicAdd(&rowsum[r0 + tid], rs);
        if (COLS) {
            float cs = 0.f;
            #pragma unroll
            for (int k = 0; k < 16; k++) cs += cpart[k][tid];
            atomicAdd(&colsum[c0 + tid], cs);
        }
    }
}

__global__ __launch_bounds__(256)
void k_invscale(float* __restrict__ s, int n, float c)
{
    const int i = blockIdx.x * 256 + threadIdx.x;
    if (i < n) s[i] = c / (s[i] + 1e-7f);
}

// Pass 2: fp8 operands in concat layouts (scales pre-folded incl 2^13 / 2^11).
template<bool TRANS>
__global__ __launch_bounds__(256)
void k_prep2f8(const float* __restrict__ in, int C,
               unsigned char* __restrict__ Aobj, unsigned char* __restrict__ Arel,
               const float* __restrict__ invRow, const float* __restrict__ invCol)
{
    __shared__ float tile[64][65];
    const int tid = threadIdx.x;
    const int tx  = tid & 15;
    const int ty  = tid >> 4;
    const long c0 = (long)blockIdx.x * 64;
    const long r0 = (long)blockIdx.y * 64;

    #pragma unroll
    for (int i = 0; i < 4; i++) {
        const int r = i * 16 + ty;
        const f32x4 v = *reinterpret_cast<const f32x4*>(&in[(r0 + r) * (long)C + c0 + tx * 4]);
        const float sc = invRow[r0 + r];
        *reinterpret_cast<unsigned*>(&Aobj[(r0 + r) * (long)KOBJ + c0 + tx * 4]) =
            pk4_fp8(v[0] * sc, v[1] * sc, v[2] * sc, v[3] * sc);
        if (TRANS) *reinterpret_cast<f32x4*>(&tile[r][tx * 4]) = v;
    }
    if (TRANS) {
        __syncthreads();
        const int rr = tid & 63;
        const int cg = tid >> 6;
        #pragma unroll
        for (int i = 0; i < 16; i++) {
            const int c = cg * 16 + i;
            const float sc = invCol[c0 + c];
            Arel[(c0 + c) * (long)KREL + r0 + rr] = fp8_byte(tile[rr][c] * sc);
        }
    }
}

extern "C" void kernel_launch(void* const* d_in, const int* in_sizes, int n_in,
                              void* d_out, int out_size, void* d_ws, size_t ws_size,
                              hipStream_t stream)
{
    if (n_in < 15) return;
    const float* obj_feats = (const float*)d_in[0];
    const float* rel_feats = (const float*)d_in[1];
    const float* attn_sub  = (const float*)d_in[2];
    const float* attn_obj  = (const float*)d_in[3];
    const float* attn_self = (const float*)d_in[4];
    const float* Wf[5] = { (const float*)d_in[5], (const float*)d_in[7],
                           (const float*)d_in[9], (const float*)d_in[11], (const float*)d_in[13] };
    const float* Bf[5] = { (const float*)d_in[6], (const float*)d_in[8],
                           (const float*)d_in[10], (const float*)d_in[12], (const float*)d_in[14] };

    const int NO = NOBJ, NR = NREL, D = DIM;

    char* w = (char*)d_ws;
    auto take = [&](size_t bytes) { char* p = w; w += bytes; return p; };
    unsigned char* Aobj8  = (unsigned char*)take((size_t)NO * KOBJ);   // [2048][34816] fp8
    unsigned char* Arel8  = (unsigned char*)take((size_t)NR * KREL);   // [16384][4096] fp8
    unsigned char* fcObj8 = (unsigned char*)take((size_t)D * KOBJ);    // [1024][34816] fp8
    unsigned char* fcRel8 = (unsigned char*)take((size_t)D * KREL);    // [1024][4096]  fp8
    bf16_t* xrel_bf = (bf16_t*)take((size_t)NR * D * 2);
    bf16_t* xobj_bf = (bf16_t*)take((size_t)NO * D * 2);
    bf16_t* Wstk01  = (bf16_t*)take((size_t)2 * D * D * 2);
    bf16_t* Wstk234 = (bf16_t*)take((size_t)3 * D * D * 2);
    float*  b01     = (float*)take((size_t)2 * D * 4);
    float*  bstk    = (float*)take((size_t)3 * D * 4);
    float*  sums    = (float*)take((size_t)(3 * NO + 2 * NR) * 4);
    float* invS     = sums;            // 2^13 * (1/3)/(rowsum+eps)
    float* invO     = sums + NO;
    float* invSelf  = sums + 2 * NO;
    float* invTS    = sums + 3 * NO;   // 2^11 * 0.5/(colsum+eps)
    float* invTO    = sums + 3 * NO + NR;
    if ((size_t)(w - (char*)d_ws) > ws_size) return;   // ws too small: fail loudly

    float* x_obj = (float*)d_out;
    float* x_rel = x_obj + (size_t)NO * D;

    hipMemcpyAsync(x_obj, obj_feats, (size_t)NO * D * 4, hipMemcpyDeviceToDevice, stream);
    hipMemcpyAsync(x_rel, rel_feats, (size_t)NR * D * 4, hipMemcpyDeviceToDevice, stream);
    hipMemcpyAsync(b01,     Bf[0], (size_t)D * 4, hipMemcpyDeviceToDevice, stream);
    hipMemcpyAsync(b01 + D, Bf[1], (size_t)D * 4, hipMemcpyDeviceToDevice, stream);
    for (int i = 0; i < 3; i++)
        hipMemcpyAsync(bstk + i * D, Bf[2 + i], (size_t)D * 4, hipMemcpyDeviceToDevice, stream);
    hipMemsetAsync(sums, 0, (size_t)(3 * NO + 2 * NR) * 4, stream);

    auto cast = [&](const float* in, bf16_t* out, long n) {
        long blocks = (n / 4 + 255) / 256; if (blocks > 4096) blocks = 4096;
        k_cast_bf16<<<dim3((unsigned)blocks), dim3(256), 0, stream>>>(in, out, n);
    };
    cast(Wf[0], Wstk01,                 (long)D * D);
    cast(Wf[1], Wstk01 + (size_t)D * D, (long)D * D);
    for (int i = 0; i < 3; i++)
        cast(Wf[2 + i], Wstk234 + (size_t)i * D * D, (long)D * D);

    // pass 1: exact f32 row/col sums
    k_sums<true><<<dim3(NR / 64, NO / 64), dim3(256), 0, stream>>>(attn_sub, NR, invS, invTS);
    k_sums<true><<<dim3(NR / 64, NO / 64), dim3(256), 0, stream>>>(attn_obj, NR, invO, invTO);
    k_sums<false><<<dim3(NO / 64, NO / 64), dim3(256), 0, stream>>>(attn_self, NO, invSelf, nullptr);
    // fold global power-of-2 into the fp8 quantization scale
    k_invscale<<<dim3((3 * NO + 255) / 256), dim3(256), 0, stream>>>(sums, 3 * NO, 8192.f / 3.f);
    k_invscale<<<dim3((2 * NR + 255) / 256), dim3(256), 0, stream>>>(sums + 3 * NO, 2 * NR, 1024.f);

    // pass 2: fp8 operands in concat layouts
    k_prep2f8<true><<<dim3(NR / 64, NO / 64), dim3(256), 0, stream>>>(
        attn_sub, NR, Aobj8, Arel8, invS, invTS);
    k_prep2f8<true><<<dim3(NR / 64, NO / 64), dim3(256), 0, stream>>>(
        attn_obj, NR, Aobj8 + 16384, Arel8 + 2048, invO, invTO);
    k_prep2f8<false><<<dim3(NO / 64, NO / 64), dim3(256), 0, stream>>>(
        attn_self, NO, Aobj8 + 32768, nullptr, invSelf, nullptr);

    for (int step = 0; step < 2; ++step) {
        cast(x_obj, xobj_bf, (long)NO * D);
        cast(x_rel, xrel_bf, (long)NR * D);

        // fcObj cols [0,32768): [f0|f1] = relu([W0;W1] @ xrel^T + b01) -> fp8
        gemm256fc<<<dim3((2 * D / 256) * (NR / 256), 1, 1), dim3(512), 0, stream>>>(
            Wstk01, xrel_bf, 2 * D, NR, D, b01, fcObj8, KOBJ, NR / 256);
        // fcRel [f2|f3] + fcObj col [32768,34816) (f4) -> fp8
        gemm_bt_f234<<<dim3(3 * D / BM, NO / BN, 1), dim3(GT), 0, stream>>>(
            Wstk234, xobj_bf, 3 * D, NO, D, bstk, fcRel8, fcObj8);

        // both collects in ONE dispatch (1024 blocks = 4/CU of work):
        // x_obj += (Aobj8 @ fcObj8^T)*2^-13 ; x_rel += (Arel8 @ fcRel8^T)*2^-11
        gemmf8_dual<<<dim3(1024), dim3(512), 0, stream>>>(
            Aobj8, fcObj8, x_obj, Arel8, fcRel8, x_rel);
    }
}

// Round 13
// 813.829 us; speedup vs baseline: 1.3765x; 1.0560x over previous
//
#include <hip/hip_runtime.h>
#include <hip/hip_bf16.h>

typedef __attribute__((ext_vector_type(4))) float  f32x4;
typedef __attribute__((ext_vector_type(8))) __bf16 bf16x8;
typedef __attribute__((ext_vector_type(4))) int    i32x4;
typedef __attribute__((ext_vector_type(8))) int    i32x8;
typedef __hip_bfloat16 bf16_t;

#define GT 256
#define BM 128
#define BN 128
#define BK 32

// problem constants
#define NOBJ 2048
#define NREL 16384
#define DIM  1024
#define KOBJ 34816   /* 16384 + 16384 + 2048 */
#define KREL 4096    /* 2048 + 2048 */

#define AS1Q __attribute__((address_space(1)))
#define AS3Q __attribute__((address_space(3)))

__device__ __forceinline__ void gload_lds16(const void* g, void* l) {
    __builtin_amdgcn_global_load_lds((AS1Q void*)const_cast<void*>(g),
                                     (AS3Q void*)l, 16, 0, 0);
}

#define MFMA_BF16 __builtin_amdgcn_mfma_f32_16x16x32_bf16
// all-ones (E8M0 = 127) block scales: plain fp8 matmul at MX rate
#define MFMA_F8(ACC, Af, Bf) \
    ACC = __builtin_amdgcn_mfma_scale_f32_16x16x128_f8f6f4( \
        Af, Bf, ACC, 0, 0, 0, 0x7F7F7F7F, 0, 0x7F7F7F7F)

__device__ __forceinline__ unsigned char fp8_byte(float x) {
    return (unsigned char)(__builtin_amdgcn_cvt_pk_fp8_f32(x, x, 0, false) & 0xFF);
}
__device__ __forceinline__ unsigned pk4_fp8(float a, float b, float c, float d) {
    int v = __builtin_amdgcn_cvt_pk_fp8_f32(a, b, 0, false);
    v = __builtin_amdgcn_cvt_pk_fp8_f32(c, d, v, true);
    return (unsigned)v;
}

// ---------------------------------------------------------------------------
// 128x128 2-phase bf16 kernel — stacked obj-side FCs; fp8 outputs (x64 for
// shared scale with fp8 fc01) routed to fcRel8 (f2,f3) / fcObj8 (f4).
// ---------------------------------------------------------------------------
__global__ __launch_bounds__(GT)
void gemm_bt_f234(const bf16_t* __restrict__ A, const bf16_t* __restrict__ B,
                  int M, int N, int K, const float* __restrict__ vecM,
                  unsigned char* __restrict__ fcRel8, unsigned char* __restrict__ fcObj8)
{
    __shared__ bf16_t sA[BM * BK];
    __shared__ bf16_t sB[BN * BK];

    const int tid  = threadIdx.x;
    const int lane = tid & 63;
    const int wid  = tid >> 6;
    const int wr = wid >> 1, wc = wid & 1;
    const int l15 = lane & 15, lk = lane >> 4;

    const long rowA0 = (long)blockIdx.x * BM;
    const long rowB0 = (long)blockIdx.y * BN;
    const long ldab  = (long)K * 2;

    const int c0 = tid, c1 = tid + GT;
    const int r0c = c0 >> 2, k0c = (c0 & 3) ^ ((r0c >> 1) & 3);
    const int r1c = c1 >> 2, k1c = (c1 & 3) ^ ((r1c >> 1) & 3);

    const char* gA0 = (const char*)A + (rowA0 + r0c) * ldab + k0c * 16;
    const char* gA1 = (const char*)A + (rowA0 + r1c) * ldab + k1c * 16;
    const char* gB0 = (const char*)B + (rowB0 + r0c) * ldab + k0c * 16;
    const char* gB1 = (const char*)B + (rowB0 + r1c) * ldab + k1c * 16;
    char* lA0 = (char*)sA + c0 * 16;
    char* lA1 = (char*)sA + c1 * 16;
    char* lB0 = (char*)sB + c0 * 16;
    char* lB1 = (char*)sB + c1 * 16;

    f32x4 acc[4][4];
    #pragma unroll
    for (int i = 0; i < 4; i++)
        #pragma unroll
        for (int j = 0; j < 4; j++) acc[i][j] = f32x4{0.f, 0.f, 0.f, 0.f};

    const int ktPer = K / BK;
    for (int kt = 0; kt < ktPer; ++kt) {
        const long kByte = (long)kt * (BK * 2);
        gload_lds16(gA0 + kByte, lA0);
        gload_lds16(gA1 + kByte, lA1);
        gload_lds16(gB0 + kByte, lB0);
        gload_lds16(gB1 + kByte, lB1);
        __syncthreads();

        bf16x8 af[4], bg[4];
        #pragma unroll
        for (int i = 0; i < 4; i++) {
            const int rr = wr * 64 + i * 16 + l15;
            const int kk = lk ^ ((rr >> 1) & 3);
            af[i] = *reinterpret_cast<const bf16x8*>((const char*)sA + rr * 64 + kk * 16);
        }
        #pragma unroll
        for (int j = 0; j < 4; j++) {
            const int rr = wc * 64 + j * 16 + l15;
            const int kk = lk ^ ((rr >> 1) & 3);
            bg[j] = *reinterpret_cast<const bf16x8*>((const char*)sB + rr * 64 + kk * 16);
        }
        #pragma unroll
        for (int i = 0; i < 4; i++)
            #pragma unroll
            for (int j = 0; j < 4; j++)
                acc[i][j] = MFMA_BF16(af[i], bg[j], acc[i][j], 0, 0, 0);
        __syncthreads();
    }

    #pragma unroll
    for (int i = 0; i < 4; i++) {
        const long mBase = rowA0 + wr * 64 + i * 16 + lk * 4;
        const f32x4 vm = *reinterpret_cast<const f32x4*>(&vecM[mBase]);
        #pragma unroll
        for (int r = 0; r < 4; r++) {
            const long m = mBase + r;
            #pragma unroll
            for (int j = 0; j < 4; j++) {
                const long n = rowB0 + wc * 64 + j * 16 + l15;
                const float v = fmaxf(acc[i][j][r] + vm[r], 0.f) * 64.f;
                const unsigned char o = fp8_byte(v);
                if (m < 1024)            fcRel8[m * (long)KREL + n] = o;
                else if (m < 2048)       fcRel8[(m - 1024) * (long)KREL + 2048 + n] = o;
                else                     fcObj8[(m - 2048) * (long)KOBJ + 32768 + n] = o;
            }
        }
    }
}

// ---------------------------------------------------------------------------
// MX-fp8 fc01 kernel, occ structure (128x256 tile, 48 KiB LDS, 512 thr).
// A = W01_8 [2048][1024] (= 64*W, fp8), B = xrel8 [16384][1024] (fp8).
// Epilogue: fp8(relu(acc + 64*bias[m])) routed to fcObj8 column slices.
// Grid 1024 = 16 m-tiles x 64 n-tiles (XCD-swizzled).
// ---------------------------------------------------------------------------
__global__ __launch_bounds__(512, 4)
void gemmf8fc(const unsigned char* __restrict__ A, const unsigned char* __restrict__ B,
              const float* __restrict__ bias, unsigned char* __restrict__ Cb8)
{
    __shared__ __align__(16) char lds[49152];   // A[128][128B] @0, B[256][128B] @16384

    const int tid  = threadIdx.x;
    const int lane = tid & 63;
    const int wid  = tid >> 6;
    const int wr = wid >> 2, wc = wid & 3;
    const int l15 = lane & 15, lk = lane >> 4;

    const int bid = blockIdx.x;                 // 1024
    const int s   = (bid & 7) * 128 + (bid >> 3);
    const long rowM0 = (long)(s >> 6) * 128;    // 16 m-tiles over 2048
    const long rowN0 = (long)(s & 63) * 256;    // 64 n-tiles over 16384
    const int  K  = 1024;
    const long ld = (long)K;
    const int  NT = K >> 7;                     // 8

    const int rs = tid >> 3;
    const int kc = (tid & 7) ^ (rs & 7);
    const char* gA = (const char*)A + (rowM0 + rs) * ld + kc * 16;
    const char* gB = (const char*)B + (rowN0 + rs) * ld + kc * 16;
    char* lA = (char*)lds + tid * 16;
    char* lB = (char*)lds + 16384 + tid * 16;

    const int xc0 = ((2 * lk + 0) ^ (l15 & 7)) * 16;
    const int xc1 = ((2 * lk + 1) ^ (l15 & 7)) * 16;
    const int baseA = (wr * 64 + l15) * 128;
    const int baseB = 16384 + (wc * 64 + l15) * 128;

#define LDF8(dst, off) { \
    i32x4 lo_ = *(const i32x4*)((const char*)lds + (off) + xc0); \
    i32x4 hi_ = *(const i32x4*)((const char*)lds + (off) + xc1); \
    dst = __builtin_shufflevector(lo_, hi_, 0, 1, 2, 3, 4, 5, 6, 7); }

    f32x4 acc[4][4];
    #pragma unroll
    for (int i = 0; i < 4; i++)
        #pragma unroll
        for (int j = 0; j < 4; j++) acc[i][j] = f32x4{0.f, 0.f, 0.f, 0.f};

    for (int t = 0; t < NT; ++t) {
        const long kByte = (long)t * 128;
        gload_lds16(gA + kByte, lA);
        gload_lds16(gA + kByte + 64 * ld, lA + 8192);
        #pragma unroll
        for (int i = 0; i < 4; i++)
            gload_lds16(gB + kByte + (long)i * 64 * ld, lB + i * 8192);
        __syncthreads();

        i32x8 a[4];
        #pragma unroll
        for (int kf = 0; kf < 4; kf++) LDF8(a[kf], baseA + kf * 2048);
        #pragma unroll
        for (int j = 0; j < 4; j++) {
            i32x8 b;
            LDF8(b, baseB + j * 2048);
            #pragma unroll
            for (int kf = 0; kf < 4; kf++) MFMA_F8(acc[kf][j], a[kf], b);
        }
        __syncthreads();
    }
#undef LDF8

    #pragma unroll
    for (int kf = 0; kf < 4; kf++) {
        const long m0 = rowM0 + wr * 64 + kf * 16 + lk * 4;
        #pragma unroll
        for (int r = 0; r < 4; r++) {
            const long m = m0 + r;
            const float bs = 64.f * bias[m];
            #pragma unroll
            for (int j = 0; j < 4; j++) {
                const long n = rowN0 + wc * 64 + j * 16 + l15;
                const float v = fmaxf(acc[kf][j][r] + bs, 0.f);
                Cb8[(m & 1023) * (long)KOBJ + (m >> 10) * 16384 + n] = fp8_byte(v);
            }
        }
    }
}

// ---------------------------------------------------------------------------
// Dual-role 128x256 MX-fp8 collect kernel (one dispatch = both collects).
// (R12 version; scales /64 to undo the x64 fc-output scaling.)
// ---------------------------------------------------------------------------
__global__ __launch_bounds__(512, 4)
void gemmf8_dual(const unsigned char* __restrict__ Ao, const unsigned char* __restrict__ Bo,
                 float* __restrict__ Co,
                 const unsigned char* __restrict__ Ar, const unsigned char* __restrict__ Br,
                 float* __restrict__ Cr)
{
    __shared__ __align__(16) char lds[49152];   // A[128][128B] @0, B[256][128B] @16384

    const int tid  = threadIdx.x;
    const int lane = tid & 63;
    const int wid  = tid >> 6;
    const int wr = wid >> 2, wc = wid & 3;
    const int l15 = lane & 15, lk = lane >> 4;

    const int bid = blockIdx.x;                 // 1024, %8==0
    const int s   = (bid & 7) * 128 + (bid >> 3);

    const unsigned char* A; const unsigned char* B; float* C;
    int K, NT; long kb0; float scale; bool at;
    long rowM0, rowN0;
    if (s < 512) {          // colObj: x_obj += (Aobj @ fcObj^T) * 2^-19
        const int zz = s >> 6, t = s & 63;      // 8 z-slices x 64 tiles (16x4)
        rowM0 = (long)(t >> 2) * 128; rowN0 = (long)(t & 3) * 256;
        A = Ao; B = Bo; C = Co;
        K = KOBJ; NT = 34; kb0 = (long)34 * zz * 128;
        scale = 1.f / (8192.f * 64.f); at = true;
    } else {                // colRel: x_rel += (Arel @ fcRel^T) * 2^-17
        const int t = s - 512;                  // 512 tiles (128x4)
        rowM0 = (long)(t >> 2) * 128; rowN0 = (long)(t & 3) * 256;
        A = Ar; B = Br; C = Cr;
        K = KREL; NT = 32; kb0 = 0;
        scale = 1.f / (2048.f * 64.f); at = false;
    }
    const long ld = (long)K;            // bytes per row

    const int rs = tid >> 3;                    // 0..63
    const int kc = (tid & 7) ^ (rs & 7);
    const char* gA = (const char*)A + (rowM0 + rs) * ld + kb0 + kc * 16;
    const char* gB = (const char*)B + (rowN0 + rs) * ld + kb0 + kc * 16;
    char* lA = (char*)lds + tid * 16;
    char* lB = (char*)lds + 16384 + tid * 16;

    const int xc0 = ((2 * lk + 0) ^ (l15 & 7)) * 16;
    const int xc1 = ((2 * lk + 1) ^ (l15 & 7)) * 16;
    const int baseA = (wr * 64 + l15) * 128;            // + kf*2048
    const int baseB = 16384 + (wc * 64 + l15) * 128;    // + j*2048

#define LDF8(dst, off) { \
    i32x4 lo_ = *(const i32x4*)((const char*)lds + (off) + xc0); \
    i32x4 hi_ = *(const i32x4*)((const char*)lds + (off) + xc1); \
    dst = __builtin_shufflevector(lo_, hi_, 0, 1, 2, 3, 4, 5, 6, 7); }

    f32x4 acc[4][4];
    #pragma unroll
    for (int i = 0; i < 4; i++)
        #pragma unroll
        for (int j = 0; j < 4; j++) acc[i][j] = f32x4{0.f, 0.f, 0.f, 0.f};

    for (int t = 0; t < NT; ++t) {
        const long kByte = (long)t * 128;
        gload_lds16(gA + kByte, lA);
        gload_lds16(gA + kByte + 64 * ld, lA + 8192);
        #pragma unroll
        for (int i = 0; i < 4; i++)
            gload_lds16(gB + kByte + (long)i * 64 * ld, lB + i * 8192);
        __syncthreads();   // compiler drains vmcnt+lgkmcnt here

        i32x8 a[4];
        #pragma unroll
        for (int kf = 0; kf < 4; kf++) LDF8(a[kf], baseA + kf * 2048);
        #pragma unroll
        for (int j = 0; j < 4; j++) {
            i32x8 b;
            LDF8(b, baseB + j * 2048);
            #pragma unroll
            for (int kf = 0; kf < 4; kf++) MFMA_F8(acc[kf][j], a[kf], b);
        }
        __syncthreads();
    }
#undef LDF8

    #pragma unroll
    for (int kf = 0; kf < 4; kf++) {
        const long m0 = rowM0 + wr * 64 + kf * 16 + lk * 4;
        #pragma unroll
        for (int r = 0; r < 4; r++) {
            const long m = m0 + r;
            #pragma unroll
            for (int j = 0; j < 4; j++) {
                const long n = rowN0 + wc * 64 + j * 16 + l15;
                const float v = acc[kf][j][r] * scale;
                if (at) atomicAdd(&C[m * (long)DIM + n], v);
                else    C[m * (long)DIM + n] += v;
            }
        }
    }
}

__global__ __launch_bounds__(256)
void k_cast_bf16(const float* __restrict__ in, bf16_t* __restrict__ out, long n)
{
    const long stride = (long)gridDim.x * blockDim.x;
    for (long i = (long)blockIdx.x * blockDim.x + threadIdx.x; i * 4 < n; i += stride) {
        f32x4 v = *reinterpret_cast<const f32x4*>(in + i * 4);
        union { bf16_t h[4]; ushort4 u; } o;
        o.h[0] = __float2bfloat16(v[0]); o.h[1] = __float2bfloat16(v[1]);
        o.h[2] = __float2bfloat16(v[2]); o.h[3] = __float2bfloat16(v[3]);
        *reinterpret_cast<ushort4*>(out + i * 4) = o.u;
    }
}

__global__ __launch_bounds__(256)
void k_cast_fp8(const float* __restrict__ in, unsigned char* __restrict__ out,
                long n, float scale)
{
    const long stride = (long)gridDim.x * blockDim.x;
    for (long i = (long)blockIdx.x * blockDim.x + threadIdx.x; i * 4 < n; i += stride) {
        f32x4 v = *reinterpret_cast<const f32x4*>(in + i * 4);
        *reinterpret_cast<unsigned*>(out + i * 4) =
            pk4_fp8(v[0] * scale, v[1] * scale, v[2] * scale, v[3] * scale);
    }
}

// Pass 1: row-sum (+ optional col-sum) partials of f32 attn via atomics.
template<bool COLS>
__global__ __launch_bounds__(256)
void k_sums(const float* __restrict__ in, int C,
            float* __restrict__ rowsum, float* __restrict__ colsum)
{
    __shared__ float cpart[16][64];
    __shared__ float rpart[64][17];
    const int tid = threadIdx.x;
    const int tx  = tid & 15;
    const int ty  = tid >> 4;
    const long c0 = (long)blockIdx.x * 64;
    const long r0 = (long)blockIdx.y * 64;

    float cs0 = 0.f, cs1 = 0.f, cs2 = 0.f, cs3 = 0.f;
    #pragma unroll
    for (int i = 0; i < 4; i++) {
        const int r = i * 16 + ty;
        const f32x4 v = *reinterpret_cast<const f32x4*>(&in[(r0 + r) * (long)C + c0 + tx * 4]);
        rpart[r][tx] = v[0] + v[1] + v[2] + v[3];
        cs0 += v[0]; cs1 += v[1]; cs2 += v[2]; cs3 += v[3];
    }
    if (COLS) {
        cpart[ty][tx * 4 + 0] = cs0;
        cpart[ty][tx * 4 + 1] = cs1;
        cpart[ty][tx * 4 + 2] = cs2;
        cpart[ty][tx * 4 + 3] = cs3;
    }
    __syncthreads();
    if (tid < 64) {
        float rs = 0.f;
        #pragma unroll
        for (int k = 0; k < 16; k++) rs += rpart[tid][k];
        atomicAdd(&rowsum[r0 + tid], rs);
        if (COLS) {
            float cs = 0.f;
            #pragma unroll
            for (int k = 0; k < 16; k++) cs += cpart[k][tid];
            atomicAdd(&colsum[c0 + tid], cs);
        }
    }
}

__global__ __launch_bounds__(256)
void k_invscale(float* __restrict__ s, int n, float c)
{
    const int i = blockIdx.x * 256 + threadIdx.x;
    if (i < n) s[i] = c / (s[i] + 1e-7f);
}

// Pass 2: fp8 operands in concat layouts (scales pre-folded incl 2^13 / 2^11).
template<bool TRANS>
__global__ __launch_bounds__(256)
void k_prep2f8(const float* __restrict__ in, int C,
               unsigned char* __restrict__ Aobj, unsigned char* __restrict__ Arel,
               const float* __restrict__ invRow, const float* __restrict__ invCol)
{
    __shared__ float tile[64][65];
    const int tid = threadIdx.x;
    const int tx  = tid & 15;
    const int ty  = tid >> 4;
    const long c0 = (long)blockIdx.x * 64;
    const long r0 = (long)blockIdx.y * 64;

    #pragma unroll
    for (int i = 0; i < 4; i++) {
        const int r = i * 16 + ty;
        const f32x4 v = *reinterpret_cast<const f32x4*>(&in[(r0 + r) * (long)C + c0 + tx * 4]);
        const float sc = invRow[r0 + r];
        *reinterpret_cast<unsigned*>(&Aobj[(r0 + r) * (long)KOBJ + c0 + tx * 4]) =
            pk4_fp8(v[0] * sc, v[1] * sc, v[2] * sc, v[3] * sc);
        if (TRANS) *reinterpret_cast<f32x4*>(&tile[r][tx * 4]) = v;
    }
    if (TRANS) {
        __syncthreads();
        const int rr = tid & 63;
        const int cg = tid >> 6;
        #pragma unroll
        for (int i = 0; i < 16; i++) {
            const int c = cg * 16 + i;
            const float sc = invCol[c0 + c];
            Arel[(c0 + c) * (long)KREL + r0 + rr] = fp8_byte(tile[rr][c] * sc);
        }
    }
}

extern "C" void kernel_launch(void* const* d_in, const int* in_sizes, int n_in,
                              void* d_out, int out_size, void* d_ws, size_t ws_size,
                              hipStream_t stream)
{
    if (n_in < 15) return;
    const float* obj_feats = (const float*)d_in[0];
    const float* rel_feats = (const float*)d_in[1];
    const float* attn_sub  = (const float*)d_in[2];
    const float* attn_obj  = (const float*)d_in[3];
    const float* attn_self = (const float*)d_in[4];
    const float* Wf[5] = { (const float*)d_in[5], (const float*)d_in[7],
                           (const float*)d_in[9], (const float*)d_in[11], (const float*)d_in[13] };
    const float* Bf[5] = { (const float*)d_in[6], (const float*)d_in[8],
                           (const float*)d_in[10], (const float*)d_in[12], (const float*)d_in[14] };

    const int NO = NOBJ, NR = NREL, D = DIM;

    char* w = (char*)d_ws;
    auto take = [&](size_t bytes) { char* p = w; w += bytes; return p; };
    unsigned char* Aobj8  = (unsigned char*)take((size_t)NO * KOBJ);   // [2048][34816] fp8
    unsigned char* Arel8  = (unsigned char*)take((size_t)NR * KREL);   // [16384][4096] fp8
    unsigned char* fcObj8 = (unsigned char*)take((size_t)D * KOBJ);    // [1024][34816] fp8
    unsigned char* fcRel8 = (unsigned char*)take((size_t)D * KREL);    // [1024][4096]  fp8
    unsigned char* xrel8  = (unsigned char*)take((size_t)NR * D);      // [16384][1024] fp8
    unsigned char* W018   = (unsigned char*)take((size_t)2 * D * D);   // [2048][1024]  fp8 (64*W)
    bf16_t* xobj_bf = (bf16_t*)take((size_t)NO * D * 2);
    bf16_t* Wstk234 = (bf16_t*)take((size_t)3 * D * D * 2);
    float*  b01     = (float*)take((size_t)2 * D * 4);
    float*  bstk    = (float*)take((size_t)3 * D * 4);
    float*  sums    = (float*)take((size_t)(3 * NO + 2 * NR) * 4);
    float* invS     = sums;            // 2^13 * (1/3)/(rowsum+eps)
    float* invO     = sums + NO;
    float* invSelf  = sums + 2 * NO;
    float* invTS    = sums + 3 * NO;   // 2^11 * 0.5/(colsum+eps)
    float* invTO    = sums + 3 * NO + NR;
    if ((size_t)(w - (char*)d_ws) > ws_size) return;   // ws too small: fail loudly

    float* x_obj = (float*)d_out;
    float* x_rel = x_obj + (size_t)NO * D;

    hipMemcpyAsync(x_obj, obj_feats, (size_t)NO * D * 4, hipMemcpyDeviceToDevice, stream);
    hipMemcpyAsync(x_rel, rel_feats, (size_t)NR * D * 4, hipMemcpyDeviceToDevice, stream);
    hipMemcpyAsync(b01,     Bf[0], (size_t)D * 4, hipMemcpyDeviceToDevice, stream);
    hipMemcpyAsync(b01 + D, Bf[1], (size_t)D * 4, hipMemcpyDeviceToDevice, stream);
    for (int i = 0; i < 3; i++)
        hipMemcpyAsync(bstk + i * D, Bf[2 + i], (size_t)D * 4, hipMemcpyDeviceToDevice, stream);
    hipMemsetAsync(sums, 0, (size_t)(3 * NO + 2 * NR) * 4, stream);

    auto castb = [&](const float* in, bf16_t* out, long n) {
        long blocks = (n / 4 + 255) / 256; if (blocks > 4096) blocks = 4096;
        k_cast_bf16<<<dim3((unsigned)blocks), dim3(256), 0, stream>>>(in, out, n);
    };
    auto cast8 = [&](const float* in, unsigned char* out, long n, float sc) {
        long blocks = (n / 4 + 255) / 256; if (blocks > 4096) blocks = 4096;
        k_cast_fp8<<<dim3((unsigned)blocks), dim3(256), 0, stream>>>(in, out, n, sc);
    };
    cast8(Wf[0], W018,                 (long)D * D, 64.f);   // 64*W0
    cast8(Wf[1], W018 + (size_t)D * D, (long)D * D, 64.f);   // 64*W1
    for (int i = 0; i < 3; i++)
        castb(Wf[2 + i], Wstk234 + (size_t)i * D * D, (long)D * D);

    // pass 1: exact f32 row/col sums
    k_sums<true><<<dim3(NR / 64, NO / 64), dim3(256), 0, stream>>>(attn_sub, NR, invS, invTS);
    k_sums<true><<<dim3(NR / 64, NO / 64), dim3(256), 0, stream>>>(attn_obj, NR, invO, invTO);
    k_sums<false><<<dim3(NO / 64, NO / 64), dim3(256), 0, stream>>>(attn_self, NO, invSelf, nullptr);
    // fold global power-of-2 into the fp8 quantization scale
    k_invscale<<<dim3((3 * NO + 255) / 256), dim3(256), 0, stream>>>(sums, 3 * NO, 8192.f / 3.f);
    k_invscale<<<dim3((2 * NR + 255) / 256), dim3(256), 0, stream>>>(sums + 3 * NO, 2 * NR, 1024.f);

    // pass 2: fp8 operands in concat layouts
    k_prep2f8<true><<<dim3(NR / 64, NO / 64), dim3(256), 0, stream>>>(
        attn_sub, NR, Aobj8, Arel8, invS, invTS);
    k_prep2f8<true><<<dim3(NR / 64, NO / 64), dim3(256), 0, stream>>>(
        attn_obj, NR, Aobj8 + 16384, Arel8 + 2048, invO, invTO);
    k_prep2f8<false><<<dim3(NO / 64, NO / 64), dim3(256), 0, stream>>>(
        attn_self, NO, Aobj8 + 32768, nullptr, invSelf, nullptr);

    for (int step = 0; step < 2; ++step) {
        castb(x_obj, xobj_bf, (long)NO * D);
        cast8(x_rel, xrel8, (long)NR * D, 1.f);

        // fcObj cols [0,32768): [f0|f1] = relu(64*W01 @ xrel^T + 64*b01) -> fp8
        gemmf8fc<<<dim3(1024), dim3(512), 0, stream>>>(W018, xrel8, b01, fcObj8);
        // fcRel [f2|f3] + fcObj col [32768,34816) (f4), x64 -> fp8
        gemm_bt_f234<<<dim3(3 * D / BM, NO / BN, 1), dim3(GT), 0, stream>>>(
            Wstk234, xobj_bf, 3 * D, NO, D, bstk, fcRel8, fcObj8);

        // both collects in ONE dispatch:
        // x_obj += (Aobj8 @ fcObj8^T)*2^-19 ; x_rel += (Arel8 @ fcRel8^T)*2^-17
        gemmf8_dual<<<dim3(1024), dim3(512), 0, stream>>>(
            Aobj8, fcObj8, x_obj, Arel8, fcRel8, x_rel);
    }
}

// Round 14
// 772.049 us; speedup vs baseline: 1.4509x; 1.0541x over previous
//
#include <hip/hip_runtime.h>
#include <hip/hip_bf16.h>

typedef __attribute__((ext_vector_type(4))) float  f32x4;
typedef __attribute__((ext_vector_type(8))) __bf16 bf16x8;
typedef __attribute__((ext_vector_type(4))) int    i32x4;
typedef __attribute__((ext_vector_type(8))) int    i32x8;
typedef __hip_bfloat16 bf16_t;

// problem constants
#define NOBJ 2048
#define NREL 16384
#define DIM  1024
#define KOBJ 34816   /* 16384 + 16384 + 2048 */
#define KREL 4096    /* 2048 + 2048 */

#define AS1Q __attribute__((address_space(1)))
#define AS3Q __attribute__((address_space(3)))

__device__ __forceinline__ void gload_lds16(const void* g, void* l) {
    __builtin_amdgcn_global_load_lds((AS1Q void*)const_cast<void*>(g),
                                     (AS3Q void*)l, 16, 0, 0);
}

// all-ones (E8M0 = 127) block scales: plain fp8 matmul at MX rate
#define MFMA_F8(ACC, Af, Bf) \
    ACC = __builtin_amdgcn_mfma_scale_f32_16x16x128_f8f6f4( \
        Af, Bf, ACC, 0, 0, 0, 0x7F7F7F7F, 0, 0x7F7F7F7F)

__device__ __forceinline__ unsigned char fp8_byte(float x) {
    return (unsigned char)(__builtin_amdgcn_cvt_pk_fp8_f32(x, x, 0, false) & 0xFF);
}
__device__ __forceinline__ unsigned pk4_fp8(float a, float b, float c, float d) {
    int v = __builtin_amdgcn_cvt_pk_fp8_f32(a, b, 0, false);
    v = __builtin_amdgcn_cvt_pk_fp8_f32(c, d, v, true);
    return (unsigned)v;
}

// ---------------------------------------------------------------------------
// Merged MX-fp8 FC kernel (fc01 + f234 in one dispatch), occ structure:
// 128x256 tile, 48 KiB LDS, 512 thr (8 waves 2Mx4N, 64x64 out), K=1024, NT=8.
// Role by swizzled id s (1216 blocks):
//   s<1024: fc01  A=W01_8[2048][1024] (64*W), B=xrel8[16384][1024], bias=b01
//           out: fcObj8[(m&1023)*KOBJ + (m>>10)*16384 + n]
//   else:   f234  A=W234_8[3072][1024] (64*W), B=xobj8[2048][1024], bias=bstk
//           out: m<1024 -> fcRel8[m*KREL+n]; m<2048 -> fcRel8[(m-1024)*KREL+2048+n];
//                else fcObj8[(m-2048)*KOBJ + 32768 + n]
// Epilogue value: fp8(relu(acc + 64*bias[m]))  (x64 convention, undone in dual)
// ---------------------------------------------------------------------------
__global__ __launch_bounds__(512, 4)
void gemmf8mlp(const unsigned char* __restrict__ W01, const unsigned char* __restrict__ xrel8,
               const unsigned char* __restrict__ W234, const unsigned char* __restrict__ xobj8,
               const float* __restrict__ b01, const float* __restrict__ bstk,
               unsigned char* __restrict__ fcObj8, unsigned char* __restrict__ fcRel8)
{
    __shared__ __align__(16) char lds[49152];   // A[128][128B] @0, B[256][128B] @16384

    const int tid  = threadIdx.x;
    const int lane = tid & 63;
    const int wid  = tid >> 6;
    const int wr = wid >> 2, wc = wid & 3;
    const int l15 = lane & 15, lk = lane >> 4;

    const int bid = blockIdx.x;                 // 1216, %8==0
    const int s   = (bid & 7) * 152 + (bid >> 3);

    const unsigned char* A; const unsigned char* B; const float* bias; bool isFC;
    long rowM0, rowN0;
    if (s < 1024) {         // fc01: 16 m-tiles x 64 n-tiles
        rowM0 = (long)(s >> 6) * 128;
        rowN0 = (long)(s & 63) * 256;
        A = W01; B = xrel8; bias = b01; isFC = true;
    } else {                // f234: 24 m-tiles x 8 n-tiles
        const int t = s - 1024;
        rowM0 = (long)(t >> 3) * 128;
        rowN0 = (long)(t & 7) * 256;
        A = W234; B = xobj8; bias = bstk; isFC = false;
    }
    const long ld = DIM;                // K = 1024 bytes per row
    const int  NT = DIM >> 7;           // 8

    const int rs = tid >> 3;
    const int kc = (tid & 7) ^ (rs & 7);
    const char* gA = (const char*)A + (rowM0 + rs) * ld + kc * 16;
    const char* gB = (const char*)B + (rowN0 + rs) * ld + kc * 16;
    char* lA = (char*)lds + tid * 16;
    char* lB = (char*)lds + 16384 + tid * 16;

    const int xc0 = ((2 * lk + 0) ^ (l15 & 7)) * 16;
    const int xc1 = ((2 * lk + 1) ^ (l15 & 7)) * 16;
    const int baseA = (wr * 64 + l15) * 128;
    const int baseB = 16384 + (wc * 64 + l15) * 128;

#define LDF8(dst, off) { \
    i32x4 lo_ = *(const i32x4*)((const char*)lds + (off) + xc0); \
    i32x4 hi_ = *(const i32x4*)((const char*)lds + (off) + xc1); \
    dst = __builtin_shufflevector(lo_, hi_, 0, 1, 2, 3, 4, 5, 6, 7); }

    f32x4 acc[4][4];
    #pragma unroll
    for (int i = 0; i < 4; i++)
        #pragma unroll
        for (int j = 0; j < 4; j++) acc[i][j] = f32x4{0.f, 0.f, 0.f, 0.f};

    for (int t = 0; t < NT; ++t) {
        const long kByte = (long)t * 128;
        gload_lds16(gA + kByte, lA);
        gload_lds16(gA + kByte + 64 * ld, lA + 8192);
        #pragma unroll
        for (int i = 0; i < 4; i++)
            gload_lds16(gB + kByte + (long)i * 64 * ld, lB + i * 8192);
        __syncthreads();

        i32x8 a[4];
        #pragma unroll
        for (int kf = 0; kf < 4; kf++) LDF8(a[kf], baseA + kf * 2048);
        #pragma unroll
        for (int j = 0; j < 4; j++) {
            i32x8 b;
            LDF8(b, baseB + j * 2048);
            #pragma unroll
            for (int kf = 0; kf < 4; kf++) MFMA_F8(acc[kf][j], a[kf], b);
        }
        __syncthreads();
    }
#undef LDF8

    #pragma unroll
    for (int kf = 0; kf < 4; kf++) {
        const long m0 = rowM0 + wr * 64 + kf * 16 + lk * 4;
        #pragma unroll
        for (int r = 0; r < 4; r++) {
            const long m = m0 + r;
            const float bs = 64.f * bias[m];
            #pragma unroll
            for (int j = 0; j < 4; j++) {
                const long n = rowN0 + wc * 64 + j * 16 + l15;
                const float v = fmaxf(acc[kf][j][r] + bs, 0.f);
                const unsigned char o = fp8_byte(v);
                if (isFC) {
                    fcObj8[(m & 1023) * (long)KOBJ + (m >> 10) * 16384 + n] = o;
                } else {
                    if (m < 1024)       fcRel8[m * (long)KREL + n] = o;
                    else if (m < 2048)  fcRel8[(m - 1024) * (long)KREL + 2048 + n] = o;
                    else                fcObj8[(m - 2048) * (long)KOBJ + 32768 + n] = o;
                }
            }
        }
    }
}

// ---------------------------------------------------------------------------
// Dual-role 128x256 MX-fp8 collect kernel (one dispatch = both collects).
// colRel epilogue additionally emits xrel8 = fp8(updated x_rel) for the next
// step's fc (single-writer, z=1).  Scales /64 undo the x64 fc convention.
// ---------------------------------------------------------------------------
__global__ __launch_bounds__(512, 4)
void gemmf8_dual(const unsigned char* __restrict__ Ao, const unsigned char* __restrict__ Bo,
                 float* __restrict__ Co,
                 const unsigned char* __restrict__ Ar, const unsigned char* __restrict__ Br,
                 float* __restrict__ Cr, unsigned char* __restrict__ xrel8out)
{
    __shared__ __align__(16) char lds[49152];   // A[128][128B] @0, B[256][128B] @16384

    const int tid  = threadIdx.x;
    const int lane = tid & 63;
    const int wid  = tid >> 6;
    const int wr = wid >> 2, wc = wid & 3;
    const int l15 = lane & 15, lk = lane >> 4;

    const int bid = blockIdx.x;                 // 1024, %8==0
    const int s   = (bid & 7) * 128 + (bid >> 3);

    const unsigned char* A; const unsigned char* B; float* C;
    int K, NT; long kb0; float scale; bool at;
    long rowM0, rowN0;
    if (s < 512) {          // colObj: x_obj += (Aobj @ fcObj^T) * 2^-19
        const int zz = s >> 6, t = s & 63;      // 8 z-slices x 64 tiles (16x4)
        rowM0 = (long)(t >> 2) * 128; rowN0 = (long)(t & 3) * 256;
        A = Ao; B = Bo; C = Co;
        K = KOBJ; NT = 34; kb0 = (long)34 * zz * 128;
        scale = 1.f / (8192.f * 64.f); at = true;
    } else {                // colRel: x_rel += (Arel @ fcRel^T) * 2^-17
        const int t = s - 512;                  // 512 tiles (128x4)
        rowM0 = (long)(t >> 2) * 128; rowN0 = (long)(t & 3) * 256;
        A = Ar; B = Br; C = Cr;
        K = KREL; NT = 32; kb0 = 0;
        scale = 1.f / (2048.f * 64.f); at = false;
    }
    const long ld = (long)K;            // bytes per row

    const int rs = tid >> 3;                    // 0..63
    const int kc = (tid & 7) ^ (rs & 7);
    const char* gA = (const char*)A + (rowM0 + rs) * ld + kb0 + kc * 16;
    const char* gB = (const char*)B + (rowN0 + rs) * ld + kb0 + kc * 16;
    char* lA = (char*)lds + tid * 16;
    char* lB = (char*)lds + 16384 + tid * 16;

    const int xc0 = ((2 * lk + 0) ^ (l15 & 7)) * 16;
    const int xc1 = ((2 * lk + 1) ^ (l15 & 7)) * 16;
    const int baseA = (wr * 64 + l15) * 128;            // + kf*2048
    const int baseB = 16384 + (wc * 64 + l15) * 128;    // + j*2048

#define LDF8(dst, off) { \
    i32x4 lo_ = *(const i32x4*)((const char*)lds + (off) + xc0); \
    i32x4 hi_ = *(const i32x4*)((const char*)lds + (off) + xc1); \
    dst = __builtin_shufflevector(lo_, hi_, 0, 1, 2, 3, 4, 5, 6, 7); }

    f32x4 acc[4][4];
    #pragma unroll
    for (int i = 0; i < 4; i++)
        #pragma unroll
        for (int j = 0; j < 4; j++) acc[i][j] = f32x4{0.f, 0.f, 0.f, 0.f};

    for (int t = 0; t < NT; ++t) {
        const long kByte = (long)t * 128;
        gload_lds16(gA + kByte, lA);
        gload_lds16(gA + kByte + 64 * ld, lA + 8192);
        #pragma unroll
        for (int i = 0; i < 4; i++)
            gload_lds16(gB + kByte + (long)i * 64 * ld, lB + i * 8192);
        __syncthreads();   // compiler drains vmcnt+lgkmcnt here

        i32x8 a[4];
        #pragma unroll
        for (int kf = 0; kf < 4; kf++) LDF8(a[kf], baseA + kf * 2048);
        #pragma unroll
        for (int j = 0; j < 4; j++) {
            i32x8 b;
            LDF8(b, baseB + j * 2048);
            #pragma unroll
            for (int kf = 0; kf < 4; kf++) MFMA_F8(acc[kf][j], a[kf], b);
        }
        __syncthreads();
    }
#undef LDF8

    #pragma unroll
    for (int kf = 0; kf < 4; kf++) {
        const long m0 = rowM0 + wr * 64 + kf * 16 + lk * 4;
        #pragma unroll
        for (int r = 0; r < 4; r++) {
            const long m = m0 + r;
            #pragma unroll
            for (int j = 0; j < 4; j++) {
                const long n = rowN0 + wc * 64 + j * 16 + l15;
                const float v = acc[kf][j][r] * scale;
                const long idx = m * (long)DIM + n;
                if (at) {
                    atomicAdd(&C[idx], v);
                } else {
                    const float nv = C[idx] + v;
                    C[idx] = nv;
                    xrel8out[idx] = fp8_byte(nv);
                }
            }
        }
    }
}

__global__ __launch_bounds__(256)
void k_cast_fp8(const float* __restrict__ in, unsigned char* __restrict__ out,
                long n, float scale)
{
    const long stride = (long)gridDim.x * blockDim.x;
    for (long i = (long)blockIdx.x * blockDim.x + threadIdx.x; i * 4 < n; i += stride) {
        f32x4 v = *reinterpret_cast<const f32x4*>(in + i * 4);
        *reinterpret_cast<unsigned*>(out + i * 4) =
            pk4_fp8(v[0] * scale, v[1] * scale, v[2] * scale, v[3] * scale);
    }
}

// Pass 1: row-sum (+ optional col-sum) partials of f32 attn via atomics.
template<bool COLS>
__global__ __launch_bounds__(256)
void k_sums(const float* __restrict__ in, int C,
            float* __restrict__ rowsum, float* __restrict__ colsum)
{
    __shared__ float cpart[16][64];
    __shared__ float rpart[64][17];
    const int tid = threadIdx.x;
    const int tx  = tid & 15;
    const int ty  = tid >> 4;
    const long c0 = (long)blockIdx.x * 64;
    const long r0 = (long)blockIdx.y * 64;

    float cs0 = 0.f, cs1 = 0.f, cs2 = 0.f, cs3 = 0.f;
    #pragma unroll
    for (int i = 0; i < 4; i++) {
        const int r = i * 16 + ty;
        const f32x4 v = *reinterpret_cast<const f32x4*>(&in[(r0 + r) * (long)C + c0 + tx * 4]);
        rpart[r][tx] = v[0] + v[1] + v[2] + v[3];
        cs0 += v[0]; cs1 += v[1]; cs2 += v[2]; cs3 += v[3];
    }
    if (COLS) {
        cpart[ty][tx * 4 + 0] = cs0;
        cpart[ty][tx * 4 + 1] = cs1;
        cpart[ty][tx * 4 + 2] = cs2;
        cpart[ty][tx * 4 + 3] = cs3;
    }
    __syncthreads();
    if (tid < 64) {
        float rs = 0.f;
        #pragma unroll
        for (int k = 0; k < 16; k++) rs += rpart[tid][k];
        atomicAdd(&rowsum[r0 + tid], rs);
        if (COLS) {
            float cs = 0.f;
            #pragma unroll
            for (int k = 0; k < 16; k++) cs += cpart[k][tid];
            atomicAdd(&colsum[c0 + tid], cs);
        }
    }
}

__global__ __launch_bounds__(256)
void k_invscale(float* __restrict__ s, int n, float c)
{
    const int i = blockIdx.x * 256 + threadIdx.x;
    if (i < n) s[i] = c / (s[i] + 1e-7f);
}

// Pass 2: fp8 operands in concat layouts (scales pre-folded incl 2^13 / 2^11).
template<bool TRANS>
__global__ __launch_bounds__(256)
void k_prep2f8(const float* __restrict__ in, int C,
               unsigned char* __restrict__ Aobj, unsigned char* __restrict__ Arel,
               const float* __restrict__ invRow, const float* __restrict__ invCol)
{
    __shared__ float tile[64][65];
    const int tid = threadIdx.x;
    const int tx  = tid & 15;
    const int ty  = tid >> 4;
    const long c0 = (long)blockIdx.x * 64;
    const long r0 = (long)blockIdx.y * 64;

    #pragma unroll
    for (int i = 0; i < 4; i++) {
        const int r = i * 16 + ty;
        const f32x4 v = *reinterpret_cast<const f32x4*>(&in[(r0 + r) * (long)C + c0 + tx * 4]);
        const float sc = invRow[r0 + r];
        *reinterpret_cast<unsigned*>(&Aobj[(r0 + r) * (long)KOBJ + c0 + tx * 4]) =
            pk4_fp8(v[0] * sc, v[1] * sc, v[2] * sc, v[3] * sc);
        if (TRANS) *reinterpret_cast<f32x4*>(&tile[r][tx * 4]) = v;
    }
    if (TRANS) {
        __syncthreads();
        const int rr = tid & 63;
        const int cg = tid >> 6;
        #pragma unroll
        for (int i = 0; i < 16; i++) {
            const int c = cg * 16 + i;
            const float sc = invCol[c0 + c];
            Arel[(c0 + c) * (long)KREL + r0 + rr] = fp8_byte(tile[rr][c] * sc);
        }
    }
}

extern "C" void kernel_launch(void* const* d_in, const int* in_sizes, int n_in,
                              void* d_out, int out_size, void* d_ws, size_t ws_size,
                              hipStream_t stream)
{
    if (n_in < 15) return;
    const float* obj_feats = (const float*)d_in[0];
    const float* rel_feats = (const float*)d_in[1];
    const float* attn_sub  = (const float*)d_in[2];
    const float* attn_obj  = (const float*)d_in[3];
    const float* attn_self = (const float*)d_in[4];
    const float* Wf[5] = { (const float*)d_in[5], (const float*)d_in[7],
                           (const float*)d_in[9], (const float*)d_in[11], (const float*)d_in[13] };
    const float* Bf[5] = { (const float*)d_in[6], (const float*)d_in[8],
                           (const float*)d_in[10], (const float*)d_in[12], (const float*)d_in[14] };

    const int NO = NOBJ, NR = NREL, D = DIM;

    char* w = (char*)d_ws;
    auto take = [&](size_t bytes) { char* p = w; w += bytes; return p; };
    unsigned char* Aobj8  = (unsigned char*)take((size_t)NO * KOBJ);   // [2048][34816] fp8
    unsigned char* Arel8  = (unsigned char*)take((size_t)NR * KREL);   // [16384][4096] fp8
    unsigned char* fcObj8 = (unsigned char*)take((size_t)D * KOBJ);    // [1024][34816] fp8
    unsigned char* fcRel8 = (unsigned char*)take((size_t)D * KREL);    // [1024][4096]  fp8
    unsigned char* xrel8  = (unsigned char*)take((size_t)NR * D);      // [16384][1024] fp8
    unsigned char* xobj8  = (unsigned char*)take((size_t)NO * D);      // [2048][1024]  fp8
    unsigned char* W018   = (unsigned char*)take((size_t)2 * D * D);   // [2048][1024]  fp8 (64*W)
    unsigned char* W2348  = (unsigned char*)take((size_t)3 * D * D);   // [3072][1024]  fp8 (64*W)
    float*  b01     = (float*)take((size_t)2 * D * 4);
    float*  bstk    = (float*)take((size_t)3 * D * 4);
    float*  sums    = (float*)take((size_t)(3 * NO + 2 * NR) * 4);
    float* invS     = sums;            // 2^13 * (1/3)/(rowsum+eps)
    float* invO     = sums + NO;
    float* invSelf  = sums + 2 * NO;
    float* invTS    = sums + 3 * NO;   // 2^11 * 0.5/(colsum+eps)
    float* invTO    = sums + 3 * NO + NR;
    if ((size_t)(w - (char*)d_ws) > ws_size) return;   // ws too small: fail loudly

    float* x_obj = (float*)d_out;
    float* x_rel = x_obj + (size_t)NO * D;

    hipMemcpyAsync(x_obj, obj_feats, (size_t)NO * D * 4, hipMemcpyDeviceToDevice, stream);
    hipMemcpyAsync(x_rel, rel_feats, (size_t)NR * D * 4, hipMemcpyDeviceToDevice, stream);
    hipMemcpyAsync(b01,     Bf[0], (size_t)D * 4, hipMemcpyDeviceToDevice, stream);
    hipMemcpyAsync(b01 + D, Bf[1], (size_t)D * 4, hipMemcpyDeviceToDevice, stream);
    for (int i = 0; i < 3; i++)
        hipMemcpyAsync(bstk + i * D, Bf[2 + i], (size_t)D * 4, hipMemcpyDeviceToDevice, stream);
    hipMemsetAsync(sums, 0, (size_t)(3 * NO + 2 * NR) * 4, stream);

    auto cast8 = [&](const float* in, unsigned char* out, long n, float sc) {
        long blocks = (n / 4 + 255) / 256; if (blocks > 4096) blocks = 4096;
        k_cast_fp8<<<dim3((unsigned)blocks), dim3(256), 0, stream>>>(in, out, n, sc);
    };
    cast8(Wf[0], W018,                 (long)D * D, 64.f);
    cast8(Wf[1], W018 + (size_t)D * D, (long)D * D, 64.f);
    for (int i = 0; i < 3; i++)
        cast8(Wf[2 + i], W2348 + (size_t)i * D * D, (long)D * D, 64.f);

    // pass 1: exact f32 row/col sums
    k_sums<true><<<dim3(NR / 64, NO / 64), dim3(256), 0, stream>>>(attn_sub, NR, invS, invTS);
    k_sums<true><<<dim3(NR / 64, NO / 64), dim3(256), 0, stream>>>(attn_obj, NR, invO, invTO);
    k_sums<false><<<dim3(NO / 64, NO / 64), dim3(256), 0, stream>>>(attn_self, NO, invSelf, nullptr);
    // fold global power-of-2 into the fp8 quantization scale
    k_invscale<<<dim3((3 * NO + 255) / 256), dim3(256), 0, stream>>>(sums, 3 * NO, 8192.f / 3.f);
    k_invscale<<<dim3((2 * NR + 255) / 256), dim3(256), 0, stream>>>(sums + 3 * NO, 2 * NR, 1024.f);

    // pass 2: fp8 operands in concat layouts
    k_prep2f8<true><<<dim3(NR / 64, NO / 64), dim3(256), 0, stream>>>(
        attn_sub, NR, Aobj8, Arel8, invS, invTS);
    k_prep2f8<true><<<dim3(NR / 64, NO / 64), dim3(256), 0, stream>>>(
        attn_obj, NR, Aobj8 + 16384, Arel8 + 2048, invO, invTO);
    k_prep2f8<false><<<dim3(NO / 64, NO / 64), dim3(256), 0, stream>>>(
        attn_self, NO, Aobj8 + 32768, nullptr, invSelf, nullptr);

    // initial fp8 snapshot of x_rel (subsequent steps get it from dual's epilogue)
    cast8(x_rel, xrel8, (long)NR * D, 1.f);

    for (int step = 0; step < 2; ++step) {
        cast8(x_obj, xobj8, (long)NO * D, 1.f);

        // all 5 FC layers in ONE dispatch (fc01 + f234 roles)
        gemmf8mlp<<<dim3(1216), dim3(512), 0, stream>>>(
            W018, xrel8, W2348, xobj8, b01, bstk, fcObj8, fcRel8);

        // both collects in ONE dispatch; colRel also emits xrel8 for next step
        gemmf8_dual<<<dim3(1024), dim3(512), 0, stream>>>(
            Aobj8, fcObj8, x_obj, Arel8, fcRel8, x_rel, xrel8);
    }
}